// Round 1
// baseline (381.998 us; speedup 1.0000x reference)
//
#include <hip/hip_runtime.h>
#include <cmath>

// Problem constants (B=4, S=4096, D=4096, E=64, K=8)
#define NTOK 16384
#define DDIM 4096
#define NEXP 64
#define TOPK 8
#define BT   64          // tokens per block (bulk)
#define DK   64          // K-chunk
#define NCHUNK (DDIM / DK)
#define EPS_GAP 2.5e-4f  // logit-gap ambiguity margin (bulk fp32 err ~4e-7)

// ---------------------------------------------------------------------------
// Kernel 1: bulk fp32 GEMM (64 tok x 64 exp per block) + sigmoid + top-10
// scan + outputs + ambiguity flagging.
// ---------------------------------------------------------------------------
__global__ __launch_bounds__(256) void bulk_kernel(
    const float* __restrict__ x, const float* __restrict__ W,
    const float* __restrict__ b, float* __restrict__ g_out,
    float* __restrict__ i_out, float* __restrict__ s_out,
    int* __restrict__ flag_cnt, int* __restrict__ flag_list, int flag_cap)
{
    __shared__ float xs[DK][BT + 4];      // [k][token], padded (272B rows, 16B aligned)
    __shared__ float wsh[DK][NEXP];       // [k][expert]
    __shared__ float ls[BT][NEXP + 1];    // logits, padded for bank-free row scan

    const int tid = threadIdx.x;
    const int ty  = tid & 15;             // expert group: experts 4*ty..4*ty+3
    const int tx  = tid >> 4;             // token group:  tokens  4*tx..4*tx+3
    const int lr  = tid >> 4;             // staging row helper
    const int lc  = tid & 15;             // staging col helper
    const int tok0 = blockIdx.x * BT;

    float4 xr[4], wr[4];

    auto load_chunk = [&](int d0) {
#pragma unroll
        for (int p = 0; p < 4; ++p) {
            int r = lr + 16 * p;
            xr[p] = *reinterpret_cast<const float4*>(
                &x[(size_t)(tok0 + r) * DDIM + d0 + 4 * lc]);
            wr[p] = *reinterpret_cast<const float4*>(
                &W[(size_t)(d0 + r) * NEXP + 4 * lc]);
        }
    };

    load_chunk(0);

    float acc[4][4];
#pragma unroll
    for (int i = 0; i < 4; ++i)
#pragma unroll
        for (int j = 0; j < 4; ++j) acc[i][j] = 0.0f;

    for (int c = 0; c < NCHUNK; ++c) {
        __syncthreads();   // previous compute done before LDS overwrite
#pragma unroll
        for (int p = 0; p < 4; ++p) {
            int r = lr + 16 * p;
            xs[4 * lc + 0][r] = xr[p].x;   // transpose x into [k][token]
            xs[4 * lc + 1][r] = xr[p].y;
            xs[4 * lc + 2][r] = xr[p].z;
            xs[4 * lc + 3][r] = xr[p].w;
            *reinterpret_cast<float4*>(&wsh[r][4 * lc]) = wr[p];
        }
        __syncthreads();
        if (c + 1 < NCHUNK) load_chunk((c + 1) * DK);  // prefetch next chunk

        float cs[4][4];
#pragma unroll
        for (int i = 0; i < 4; ++i)
#pragma unroll
            for (int j = 0; j < 4; ++j) cs[i][j] = 0.0f;

#pragma unroll 8
        for (int k = 0; k < DK; ++k) {
            float4 xv = *reinterpret_cast<const float4*>(&xs[k][4 * tx]);
            float4 wv = *reinterpret_cast<const float4*>(&wsh[k][4 * ty]);
            float xa[4] = {xv.x, xv.y, xv.z, xv.w};
            float wa[4] = {wv.x, wv.y, wv.z, wv.w};
#pragma unroll
            for (int i = 0; i < 4; ++i)
#pragma unroll
                for (int j = 0; j < 4; ++j)
                    cs[i][j] = fmaf(xa[i], wa[j], cs[i][j]);
        }
        // chunk sub-sum -> main acc (cuts accumulation error ~4x)
#pragma unroll
        for (int i = 0; i < 4; ++i)
#pragma unroll
            for (int j = 0; j < 4; ++j) acc[i][j] += cs[i][j];
    }

    // epilogue: add bias, write s (sigmoid), stash logits in LDS
    float be[4];
#pragma unroll
    for (int j = 0; j < 4; ++j) be[j] = b[4 * ty + j];

#pragma unroll
    for (int i = 0; i < 4; ++i) {
        float lg[4];
        float4 sv;
#pragma unroll
        for (int j = 0; j < 4; ++j) lg[j] = acc[i][j] + be[j];
        sv.x = 1.0f / (1.0f + expf(-lg[0]));
        sv.y = 1.0f / (1.0f + expf(-lg[1]));
        sv.z = 1.0f / (1.0f + expf(-lg[2]));
        sv.w = 1.0f / (1.0f + expf(-lg[3]));
        *reinterpret_cast<float4*>(
            &s_out[(size_t)(tok0 + 4 * tx + i) * NEXP + 4 * ty]) = sv;
#pragma unroll
        for (int j = 0; j < 4; ++j) ls[4 * tx + i][4 * ty + j] = lg[j];
    }
    __syncthreads();

    // top-10 scan (one lane per token, wave 0 only)
    if (tid < BT) {
        const int t = tid;
        float val[10];
        int   idx[10];
#pragma unroll
        for (int j = 0; j < 10; ++j) { val[j] = -1e30f; idx[j] = 0; }

        for (int e = 0; e < NEXP; ++e) {
            float v = ls[t][e];
            int  ei = e;
#pragma unroll
            for (int j = 0; j < 10; ++j) {
                // strict > : equal values keep lower index first (stable, jax semantics)
                if (v > val[j]) {
                    float tv = val[j]; val[j] = v; v = tv;
                    int   ti = idx[j]; idx[j] = ei; ei = ti;
                }
            }
        }

        bool flag = false;
#pragma unroll
        for (int j = 0; j < 9; ++j) flag |= (val[j] - val[j + 1]) < EPS_GAP;

        float g[TOPK], gsum = 0.0f;
#pragma unroll
        for (int j = 0; j < TOPK; ++j) {
            g[j] = 1.0f / (1.0f + expf(-val[j]));
            gsum += g[j];
        }
        const float inv = 1.0f / gsum;
        const int tg = tok0 + t;
#pragma unroll
        for (int j = 0; j < TOPK; ++j) {
            g_out[(size_t)tg * TOPK + j] = g[j] * inv;
            i_out[(size_t)tg * TOPK + j] = (float)idx[j];
        }
        if (flag) {
            int p = atomicAdd(flag_cnt, 1);
            if (p < flag_cap) flag_list[p] = tg;
        }
    }
}

// ---------------------------------------------------------------------------
// Kernel 2: f64-exact re-rank of ambiguous tokens (one token per block-iter).
// ---------------------------------------------------------------------------
__global__ __launch_bounds__(256) void refine_kernel(
    const float* __restrict__ x, const float* __restrict__ W,
    const float* __restrict__ b, float* __restrict__ g_out,
    float* __restrict__ i_out, float* __restrict__ s_out,
    const int* __restrict__ flag_cnt, const int* __restrict__ flag_list,
    int flag_cap)
{
    __shared__ float  xs2[DDIM];
    __shared__ double red[4][NEXP];
    __shared__ double sc[NEXP];

    const int tid = threadIdx.x;
    int count = *flag_cnt;
    if (count > flag_cap) count = flag_cap;

    for (int it = blockIdx.x; it < count; it += gridDim.x) {
        const int tok = flag_list[it];
        __syncthreads();   // protect LDS reuse across iterations
#pragma unroll
        for (int q = 0; q < 4; ++q) {
            int fi = tid + 256 * q;
            *reinterpret_cast<float4*>(&xs2[fi * 4]) =
                *reinterpret_cast<const float4*>(&x[(size_t)tok * DDIM + fi * 4]);
        }
        __syncthreads();

        const int e    = tid & 63;
        const int part = tid >> 6;        // 4 parts x 1024 d each
        const int dbase = part * (DDIM / 4);
        double a = 0.0;
        for (int d = 0; d < DDIM / 4; ++d) {
            a = fma((double)xs2[dbase + d],
                    (double)W[(size_t)(dbase + d) * NEXP + e], a);
        }
        red[part][e] = a;
        __syncthreads();

        if (tid < NEXP) {
            double z = ((red[0][tid] + red[1][tid]) +
                        (red[2][tid] + red[3][tid])) + (double)b[tid];
            double s = 1.0 / (1.0 + exp(-z));
            sc[tid] = s;
            s_out[(size_t)tok * NEXP + tid] = (float)s;
        }
        __syncthreads();

        if (tid == 0) {
            double val[TOPK];
            int    idx[TOPK];
#pragma unroll
            for (int j = 0; j < TOPK; ++j) { val[j] = -1e30; idx[j] = 0; }
            for (int e2 = 0; e2 < NEXP; ++e2) {
                double v = sc[e2];
                int   ei = e2;
#pragma unroll
                for (int j = 0; j < TOPK; ++j) {
                    if (v > val[j]) {
                        double tv = val[j]; val[j] = v; v = tv;
                        int    ti = idx[j]; idx[j] = ei; ei = ti;
                    }
                }
            }
            double gsum = 0.0;
#pragma unroll
            for (int j = 0; j < TOPK; ++j) gsum += val[j];
            const double inv = 1.0 / gsum;
#pragma unroll
            for (int j = 0; j < TOPK; ++j) {
                g_out[(size_t)tok * TOPK + j] = (float)(val[j] * inv);
                i_out[(size_t)tok * TOPK + j] = (float)idx[j];
            }
        }
        __syncthreads();
    }
}

// ---------------------------------------------------------------------------
extern "C" void kernel_launch(void* const* d_in, const int* in_sizes, int n_in,
                              void* d_out, int out_size, void* d_ws, size_t ws_size,
                              hipStream_t stream)
{
    (void)in_sizes; (void)n_in; (void)out_size;
    const float* x = (const float*)d_in[0];
    const float* W = (const float*)d_in[1];
    const float* b = (const float*)d_in[2];

    float* g_out = (float*)d_out;                       // [NTOK, 8]
    float* i_out = g_out + (size_t)NTOK * TOPK;         // [NTOK, 8] (indices as float)
    float* s_out = i_out + (size_t)NTOK * TOPK;         // [NTOK, 64]

    int* cnt  = (int*)d_ws;
    int* list = cnt + 4;
    int cap = (int)((ws_size > 16 ? ws_size - 16 : 0) / sizeof(int));
    if (cap > NTOK) cap = NTOK;

    hipMemsetAsync(d_ws, 0, 16, stream);
    bulk_kernel<<<NTOK / BT, 256, 0, stream>>>(x, W, b, g_out, i_out, s_out,
                                               cnt, list, cap);
    refine_kernel<<<128, 256, 0, stream>>>(x, W, b, g_out, i_out, s_out,
                                           cnt, list, cap);
}

// Round 2
// 378.834 us; speedup vs baseline: 1.0084x; 1.0084x over previous
//
#include <hip/hip_runtime.h>
#include <cmath>

// Problem constants (B=4, S=4096, D=4096, E=64, K=8)
#define NTOK 16384
#define DDIM 4096
#define NEXP 64
#define TOPK 8
#define EPS_GAP 2.5e-4f   // logit-gap ambiguity margin; bf16x2 GEMM err ~2-4e-5

typedef __attribute__((ext_vector_type(8))) short short8;   // 8 bf16 (4 VGPRs)
typedef __attribute__((ext_vector_type(4))) float f32x4;

__device__ __forceinline__ unsigned short f2bf(float f) {   // fp32 -> bf16 (RNE)
    unsigned u = __builtin_bit_cast(unsigned, f);
    u += 0x7FFFu + ((u >> 16) & 1u);
    return (unsigned short)(u >> 16);
}
__device__ __forceinline__ float bf2f(unsigned short h) {
    return __builtin_bit_cast(float, ((unsigned)h) << 16);
}

// ---------------------------------------------------------------------------
// Kernel 0: W[4096][64] fp32 -> transposed bf16 hi/lo: Wt[64 experts][4096 k]
// ---------------------------------------------------------------------------
__global__ __launch_bounds__(256) void prep_w(const float* __restrict__ W,
                                              unsigned short* __restrict__ wt_hi,
                                              unsigned short* __restrict__ wt_lo)
{
    __shared__ float tile[64][65];
    const int t = threadIdx.x;
    const int k0 = blockIdx.x * 64;
    {
        const int r = t >> 2, q = t & 3;    // 4 threads per k-row, 16 floats each
#pragma unroll
        for (int p = 0; p < 4; ++p) {
            float4 v = *reinterpret_cast<const float4*>(
                &W[(size_t)(k0 + r) * NEXP + q * 16 + p * 4]);
            tile[r][q * 16 + p * 4 + 0] = v.x;
            tile[r][q * 16 + p * 4 + 1] = v.y;
            tile[r][q * 16 + p * 4 + 2] = v.z;
            tile[r][q * 16 + p * 4 + 3] = v.w;
        }
    }
    __syncthreads();
    {
        const int e = t >> 2, kq = t & 3;   // expert row, 16-k slice
        short8 hv[2], lv[2];
#pragma unroll
        for (int half = 0; half < 2; ++half) {
#pragma unroll
            for (int kk = 0; kk < 8; ++kk) {
                float f = tile[kq * 16 + half * 8 + kk][e];
                unsigned short h = f2bf(f);
                hv[half][kk] = (short)h;
                lv[half][kk] = (short)f2bf(f - bf2f(h));
            }
        }
        size_t base = (size_t)e * DDIM + k0 + kq * 16;
        *reinterpret_cast<short8*>(&wt_hi[base + 0]) = hv[0];
        *reinterpret_cast<short8*>(&wt_hi[base + 8]) = hv[1];
        *reinterpret_cast<short8*>(&wt_lo[base + 0]) = lv[0];
        *reinterpret_cast<short8*>(&wt_lo[base + 8]) = lv[1];
    }
}

// ---------------------------------------------------------------------------
// Kernel 1: bulk MFMA GEMM (bf16 hi/lo, fp32 acc) + sigmoid + top-10 + flag.
// 256 blocks x 256 thr (4 waves); wave = 16 tokens x 64 experts.
// No LDS / no barriers in the K loop.
// ---------------------------------------------------------------------------
__global__ __launch_bounds__(256) void bulk_kernel(
    const float* __restrict__ x,
    const unsigned short* __restrict__ wt_hi,
    const unsigned short* __restrict__ wt_lo,
    const float* __restrict__ b,
    float* __restrict__ g_out, float* __restrict__ i_out,
    float* __restrict__ s_out,
    int* __restrict__ flag_cnt, int* __restrict__ flag_list, int flag_cap)
{
    __shared__ float ls[64][NEXP + 1];   // logits per block (64 tokens)

    const int tid  = threadIdx.x;
    const int l    = tid & 63;
    const int wid  = tid >> 6;
    const int tok0 = blockIdx.x * 64;
    const int wtok = tok0 + wid * 16;

    const int lrow = l & 15;             // token-within-frag / expert base
    const int kgrp = l >> 4;             // 0..3, covers k-offset 8*kgrp
    const int koff = kgrp * 8;

    const float* xrow = x + (size_t)(wtok + lrow) * DDIM + koff;
    const unsigned short* wh_base = wt_hi + (size_t)lrow * DDIM;
    const unsigned short* wl_base = wt_lo + (size_t)lrow * DDIM;

    f32x4 acc[4];
#pragma unroll
    for (int n = 0; n < 4; ++n) acc[n] = (f32x4){0.f, 0.f, 0.f, 0.f};

    auto lda = [&](int kc, float4& A0, float4& A1) {
        const float* p = xrow + (size_t)kc * 32;
        A0 = *reinterpret_cast<const float4*>(p);
        A1 = *reinterpret_cast<const float4*>(p + 4);
    };

    auto process = [&](const float4& A0, const float4& A1, int kc) {
        float av[8] = {A0.x, A0.y, A0.z, A0.w, A1.x, A1.y, A1.z, A1.w};
        short8 ah, al;
#pragma unroll
        for (int j = 0; j < 8; ++j) {
            unsigned short h = f2bf(av[j]);
            ah[j] = (short)h;
            al[j] = (short)f2bf(av[j] - bf2f(h));
        }
        const size_t kb = (size_t)kc * 32 + koff;
#pragma unroll
        for (int n = 0; n < 4; ++n) {
            short8 bh = *reinterpret_cast<const short8*>(&wh_base[(size_t)n * 16 * DDIM + kb]);
            short8 bl = *reinterpret_cast<const short8*>(&wl_base[(size_t)n * 16 * DDIM + kb]);
            acc[n] = __builtin_amdgcn_mfma_f32_16x16x32_bf16(ah, bh, acc[n], 0, 0, 0);
            acc[n] = __builtin_amdgcn_mfma_f32_16x16x32_bf16(ah, bl, acc[n], 0, 0, 0);
            acc[n] = __builtin_amdgcn_mfma_f32_16x16x32_bf16(al, bh, acc[n], 0, 0, 0);
        }
    };

    // 2-deep A prefetch pipeline over 128 K-steps of 32
    float4 a00, a01, a10, a11;
    lda(0, a00, a01);
    lda(1, a10, a11);
    for (int kc2 = 0; kc2 < 64; ++kc2) {
        const int kc = 2 * kc2;
        process(a00, a01, kc);
        int nk = (kc + 2 < 128) ? kc + 2 : 126;   // clamped dummy reload at tail
        lda(nk, a00, a01);
        process(a10, a11, kc + 1);
        nk = (kc + 3 < 128) ? kc + 3 : 127;
        lda(nk, a10, a11);
    }

    // epilogue: bias, sigmoid -> s_out, logits -> LDS
#pragma unroll
    for (int n = 0; n < 4; ++n) {
        const int e = lrow + 16 * n;
        const float be = b[e];
#pragma unroll
        for (int r = 0; r < 4; ++r) {
            const int m = kgrp * 4 + r;           // token row within wave tile
            const float logit = acc[n][r] + be;
            ls[wid * 16 + m][e] = logit;
            s_out[(size_t)(wtok + m) * NEXP + e] = 1.0f / (1.0f + __expf(-logit));
        }
    }
    __syncthreads();

    // top-10 scan, one lane per token (wave 0)
    if (tid < 64) {
        const int t = tid;
        float val[10];
        int   idx[10];
#pragma unroll
        for (int j = 0; j < 10; ++j) { val[j] = -1e30f; idx[j] = 0; }

        for (int e = 0; e < NEXP; ++e) {
            float v = ls[t][e];
            int  ei = e;
#pragma unroll
            for (int j = 0; j < 10; ++j) {
                if (v > val[j]) {    // strict > keeps lower index first on ties
                    float tv = val[j]; val[j] = v; v = tv;
                    int   ti = idx[j]; idx[j] = ei; ei = ti;
                }
            }
        }

        bool flag = false;
#pragma unroll
        for (int j = 0; j < 9; ++j) flag |= (val[j] - val[j + 1]) < EPS_GAP;

        float g[TOPK], gsum = 0.0f;
#pragma unroll
        for (int j = 0; j < TOPK; ++j) {
            g[j] = 1.0f / (1.0f + __expf(-val[j]));
            gsum += g[j];
        }
        const float inv = 1.0f / gsum;
        const int tg = tok0 + t;
#pragma unroll
        for (int j = 0; j < TOPK; ++j) {
            g_out[(size_t)tg * TOPK + j] = g[j] * inv;
            i_out[(size_t)tg * TOPK + j] = (float)idx[j];
        }
        if (flag) {
            int p = atomicAdd(flag_cnt, 1);
            if (p < flag_cap) flag_list[p] = tg;
        }
    }
}

// ---------------------------------------------------------------------------
// Kernel 2: f64-exact re-rank of ambiguous tokens.
// ---------------------------------------------------------------------------
__global__ __launch_bounds__(256) void refine_kernel(
    const float* __restrict__ x, const float* __restrict__ W,
    const float* __restrict__ b, float* __restrict__ g_out,
    float* __restrict__ i_out, float* __restrict__ s_out,
    const int* __restrict__ flag_cnt, const int* __restrict__ flag_list,
    int flag_cap)
{
    __shared__ float  xs2[DDIM];
    __shared__ double red[4][NEXP];
    __shared__ double sc[NEXP];

    const int tid = threadIdx.x;
    int count = *flag_cnt;
    if (count > flag_cap) count = flag_cap;

    for (int it = blockIdx.x; it < count; it += gridDim.x) {
        const int tok = flag_list[it];
        __syncthreads();
#pragma unroll
        for (int q = 0; q < 4; ++q) {
            int fi = tid + 256 * q;
            *reinterpret_cast<float4*>(&xs2[fi * 4]) =
                *reinterpret_cast<const float4*>(&x[(size_t)tok * DDIM + fi * 4]);
        }
        __syncthreads();

        const int e    = tid & 63;
        const int part = tid >> 6;
        const int dbase = part * (DDIM / 4);
        double a = 0.0;
        for (int d = 0; d < DDIM / 4; ++d) {
            a = fma((double)xs2[dbase + d],
                    (double)W[(size_t)(dbase + d) * NEXP + e], a);
        }
        red[part][e] = a;
        __syncthreads();

        if (tid < NEXP) {
            double z = ((red[0][tid] + red[1][tid]) +
                        (red[2][tid] + red[3][tid])) + (double)b[tid];
            double s = 1.0 / (1.0 + exp(-z));
            sc[tid] = s;
            s_out[(size_t)tok * NEXP + tid] = (float)s;
        }
        __syncthreads();

        if (tid == 0) {
            double val[TOPK];
            int    idx[TOPK];
#pragma unroll
            for (int j = 0; j < TOPK; ++j) { val[j] = -1e30; idx[j] = 0; }
            for (int e2 = 0; e2 < NEXP; ++e2) {
                double v = sc[e2];
                int   ei = e2;
#pragma unroll
                for (int j = 0; j < TOPK; ++j) {
                    if (v > val[j]) {
                        double tv = val[j]; val[j] = v; v = tv;
                        int    ti = idx[j]; idx[j] = ei; ei = ti;
                    }
                }
            }
            double gsum = 0.0;
#pragma unroll
            for (int j = 0; j < TOPK; ++j) gsum += val[j];
            const double inv = 1.0 / gsum;
#pragma unroll
            for (int j = 0; j < TOPK; ++j) {
                g_out[(size_t)tok * TOPK + j] = (float)(val[j] * inv);
                i_out[(size_t)tok * TOPK + j] = (float)idx[j];
            }
        }
        __syncthreads();
    }
}

// ---------------------------------------------------------------------------
extern "C" void kernel_launch(void* const* d_in, const int* in_sizes, int n_in,
                              void* d_out, int out_size, void* d_ws, size_t ws_size,
                              hipStream_t stream)
{
    (void)in_sizes; (void)n_in; (void)out_size;
    const float* x = (const float*)d_in[0];
    const float* W = (const float*)d_in[1];
    const float* b = (const float*)d_in[2];

    float* g_out = (float*)d_out;                       // [NTOK, 8]
    float* i_out = g_out + (size_t)NTOK * TOPK;         // [NTOK, 8] indices as float
    float* s_out = i_out + (size_t)NTOK * TOPK;         // [NTOK, 64]

    // workspace layout
    const size_t OFF_LIST = 16;
    const size_t OFF_WHI  = 131072;                      // 128 KB
    const size_t OFF_WLO  = OFF_WHI + (size_t)NEXP * DDIM * 2;  // +512 KB
    const size_t WS_NEED  = OFF_WLO + (size_t)NEXP * DDIM * 2;  // ~1.13 MB
    if (ws_size < WS_NEED) return;   // fail loudly rather than corrupt

    char* ws = (char*)d_ws;
    int* cnt  = (int*)ws;
    int* list = (int*)(ws + OFF_LIST);
    unsigned short* wt_hi = (unsigned short*)(ws + OFF_WHI);
    unsigned short* wt_lo = (unsigned short*)(ws + OFF_WLO);
    int cap = NTOK;

    hipMemsetAsync(cnt, 0, 16, stream);
    prep_w<<<DDIM / 64, 256, 0, stream>>>(W, wt_hi, wt_lo);
    bulk_kernel<<<NTOK / 64, 256, 0, stream>>>(x, wt_hi, wt_lo, b,
                                               g_out, i_out, s_out,
                                               cnt, list, cap);
    refine_kernel<<<256, 256, 0, stream>>>(x, W, b, g_out, i_out, s_out,
                                           cnt, list, cap);
}

// Round 3
// 313.885 us; speedup vs baseline: 1.2170x; 1.2069x over previous
//
#include <hip/hip_runtime.h>
#include <cmath>

// Problem constants (B=4, S=4096, D=4096, E=64, K=8)
#define NTOK 16384
#define DDIM 4096
#define NEXP 64
#define TOPK 8
#define TPB  32                  // tokens per block
#define WPB  8                   // waves per block (K-split ways)
#define KSL  (DDIM / WPB)        // 512 K per wave
#define KCPW (KSL / 32)          // 16 k-steps of 32 per wave
#define EPS_GAP 2.5e-4f          // logit-gap ambiguity margin; bf16x2 err ~2-4e-5

typedef __attribute__((ext_vector_type(8))) short short8;   // 8 bf16 (4 VGPRs)
typedef __attribute__((ext_vector_type(4))) float f32x4;

__device__ __forceinline__ unsigned short f2bf(float f) {   // fp32 -> bf16 (RNE)
    unsigned u = __builtin_bit_cast(unsigned, f);
    u += 0x7FFFu + ((u >> 16) & 1u);
    return (unsigned short)(u >> 16);
}
__device__ __forceinline__ float bf2f(unsigned short h) {
    return __builtin_bit_cast(float, ((unsigned)h) << 16);
}

// ---------------------------------------------------------------------------
// Kernel 0: W[4096][64] fp32 -> transposed bf16 hi/lo: Wt[64 experts][4096 k]
// ---------------------------------------------------------------------------
__global__ __launch_bounds__(256) void prep_w(const float* __restrict__ W,
                                              unsigned short* __restrict__ wt_hi,
                                              unsigned short* __restrict__ wt_lo)
{
    __shared__ float tile[64][65];
    const int t = threadIdx.x;
    const int k0 = blockIdx.x * 64;
    {
        const int r = t >> 2, q = t & 3;
#pragma unroll
        for (int p = 0; p < 4; ++p) {
            float4 v = *reinterpret_cast<const float4*>(
                &W[(size_t)(k0 + r) * NEXP + q * 16 + p * 4]);
            tile[r][q * 16 + p * 4 + 0] = v.x;
            tile[r][q * 16 + p * 4 + 1] = v.y;
            tile[r][q * 16 + p * 4 + 2] = v.z;
            tile[r][q * 16 + p * 4 + 3] = v.w;
        }
    }
    __syncthreads();
    {
        const int e = t >> 2, kq = t & 3;
        short8 hv[2], lv[2];
#pragma unroll
        for (int half = 0; half < 2; ++half) {
#pragma unroll
            for (int kk = 0; kk < 8; ++kk) {
                float f = tile[kq * 16 + half * 8 + kk][e];
                unsigned short h = f2bf(f);
                hv[half][kk] = (short)h;
                lv[half][kk] = (short)f2bf(f - bf2f(h));
            }
        }
        size_t base = (size_t)e * DDIM + k0 + kq * 16;
        *reinterpret_cast<short8*>(&wt_hi[base + 0]) = hv[0];
        *reinterpret_cast<short8*>(&wt_hi[base + 8]) = hv[1];
        *reinterpret_cast<short8*>(&wt_lo[base + 0]) = lv[0];
        *reinterpret_cast<short8*>(&wt_lo[base + 8]) = lv[1];
    }
}

// ---------------------------------------------------------------------------
// Kernel 1: bulk MFMA GEMM, K-split 8 ways across waves + LDS reduce.
// 512 blocks x 512 thr (8 waves). Block = 32 tokens x 64 experts.
// Wave w covers K in [w*512, w*512+512).
// ---------------------------------------------------------------------------
__global__ __launch_bounds__(512, 4) void bulk_kernel(
    const float* __restrict__ x,
    const unsigned short* __restrict__ wt_hi,
    const unsigned short* __restrict__ wt_lo,
    const float* __restrict__ b,
    float* __restrict__ g_out, float* __restrict__ i_out,
    float* __restrict__ s_out,
    int* __restrict__ flag_cnt, int* __restrict__ flag_list, int flag_cap)
{
    __shared__ float red[WPB][TPB][NEXP];   // 64 KB partial accumulators
    __shared__ float ls[TPB][NEXP + 1];     // padded logits for the scan

    const int tid  = threadIdx.x;
    const int l    = tid & 63;
    const int wid  = tid >> 6;
    const int tok0 = blockIdx.x * TPB;

    const int lrow = l & 15;
    const int kgrp = l >> 4;
    const int koff = kgrp * 8;
    const int kbase = wid * KSL;

    const float* xrow0 = x + (size_t)(tok0 + lrow) * DDIM + kbase + koff;
    const float* xrow1 = xrow0 + (size_t)16 * DDIM;
    const unsigned short* whb = wt_hi + (size_t)lrow * DDIM + kbase + koff;
    const unsigned short* wlb = wt_lo + (size_t)lrow * DDIM + kbase + koff;

    f32x4 acc[2][4];
#pragma unroll
    for (int m = 0; m < 2; ++m)
#pragma unroll
        for (int n = 0; n < 4; ++n) acc[m][n] = (f32x4){0.f, 0.f, 0.f, 0.f};

    auto ldA = [&](int kc, float4* A) {     // A[0..1]=frag0, A[2..3]=frag1
        const float* p0 = xrow0 + (size_t)kc * 32;
        A[0] = *reinterpret_cast<const float4*>(p0);
        A[1] = *reinterpret_cast<const float4*>(p0 + 4);
        const float* p1 = xrow1 + (size_t)kc * 32;
        A[2] = *reinterpret_cast<const float4*>(p1);
        A[3] = *reinterpret_cast<const float4*>(p1 + 4);
    };
    auto conv = [&](const float4* A, short8* ah, short8* al) {
#pragma unroll
        for (int m = 0; m < 2; ++m) {
            float av[8] = {A[2 * m].x, A[2 * m].y, A[2 * m].z, A[2 * m].w,
                           A[2 * m + 1].x, A[2 * m + 1].y, A[2 * m + 1].z, A[2 * m + 1].w};
#pragma unroll
            for (int j = 0; j < 8; ++j) {
                unsigned short h = f2bf(av[j]);
                ah[m][j] = (short)h;
                al[m][j] = (short)f2bf(av[j] - bf2f(h));
            }
        }
    };
    auto process = [&](const short8* ah, const short8* al, int kc) {
        const size_t kb = (size_t)kc * 32;
#pragma unroll
        for (int n = 0; n < 4; ++n) {
            short8 bh = *reinterpret_cast<const short8*>(&whb[(size_t)n * 16 * DDIM + kb]);
            short8 bl = *reinterpret_cast<const short8*>(&wlb[(size_t)n * 16 * DDIM + kb]);
#pragma unroll
            for (int m = 0; m < 2; ++m) {
                acc[m][n] = __builtin_amdgcn_mfma_f32_16x16x32_bf16(ah[m], bh, acc[m][n], 0, 0, 0);
                acc[m][n] = __builtin_amdgcn_mfma_f32_16x16x32_bf16(ah[m], bl, acc[m][n], 0, 0, 0);
                acc[m][n] = __builtin_amdgcn_mfma_f32_16x16x32_bf16(al[m], bh, acc[m][n], 0, 0, 0);
            }
        }
    };

    // 2-deep A prefetch over 16 k-steps
    float4 A0[4], A1[4];
    short8 ah[2], al[2];
    ldA(0, A0);
    ldA(1, A1);
    for (int kc2 = 0; kc2 < KCPW / 2; ++kc2) {
        const int kc = 2 * kc2;
        conv(A0, ah, al);
        ldA((kc + 2 < KCPW) ? kc + 2 : KCPW - 2, A0);
        process(ah, al, kc);
        conv(A1, ah, al);
        ldA((kc + 3 < KCPW) ? kc + 3 : KCPW - 1, A1);
        process(ah, al, kc + 1);
    }

    // partial accumulators -> LDS
#pragma unroll
    for (int m = 0; m < 2; ++m)
#pragma unroll
        for (int n = 0; n < 4; ++n)
#pragma unroll
            for (int r = 0; r < 4; ++r)
                red[wid][m * 16 + kgrp * 4 + r][n * 16 + lrow] = acc[m][n][r];
    __syncthreads();

    // deterministic fixed-order reduce + bias + sigmoid + s_out write
    {
        const int t  = tid >> 4;           // token 0..31
        const int e0 = (tid & 15) * 4;     // expert base 0..60
        float s0 = red[0][t][e0 + 0], s1 = red[0][t][e0 + 1];
        float s2 = red[0][t][e0 + 2], s3 = red[0][t][e0 + 3];
#pragma unroll
        for (int w = 1; w < WPB; ++w) {
            s0 += red[w][t][e0 + 0];
            s1 += red[w][t][e0 + 1];
            s2 += red[w][t][e0 + 2];
            s3 += red[w][t][e0 + 3];
        }
        float4 bv = *reinterpret_cast<const float4*>(&b[e0]);
        s0 += bv.x; s1 += bv.y; s2 += bv.z; s3 += bv.w;
        ls[t][e0 + 0] = s0; ls[t][e0 + 1] = s1;
        ls[t][e0 + 2] = s2; ls[t][e0 + 3] = s3;
        float4 sv;
        sv.x = 1.0f / (1.0f + __expf(-s0));
        sv.y = 1.0f / (1.0f + __expf(-s1));
        sv.z = 1.0f / (1.0f + __expf(-s2));
        sv.w = 1.0f / (1.0f + __expf(-s3));
        *reinterpret_cast<float4*>(&s_out[(size_t)(tok0 + t) * NEXP + e0]) = sv;
    }
    __syncthreads();

    // top-10 scan, one lane per token (32 lanes of wave 0)
    if (tid < TPB) {
        const int t = tid;
        float val[10];
        int   idx[10];
#pragma unroll
        for (int j = 0; j < 10; ++j) { val[j] = -1e30f; idx[j] = 0; }

        for (int e = 0; e < NEXP; ++e) {
            float v = ls[t][e];
            int  ei = e;
#pragma unroll
            for (int j = 0; j < 10; ++j) {
                if (v > val[j]) {    // strict > keeps lower index first on ties
                    float tv = val[j]; val[j] = v; v = tv;
                    int   ti = idx[j]; idx[j] = ei; ei = ti;
                }
            }
        }

        bool flag = false;
#pragma unroll
        for (int j = 0; j < 9; ++j) flag |= (val[j] - val[j + 1]) < EPS_GAP;

        float g[TOPK], gsum = 0.0f;
#pragma unroll
        for (int j = 0; j < TOPK; ++j) {
            g[j] = 1.0f / (1.0f + __expf(-val[j]));
            gsum += g[j];
        }
        const float inv = 1.0f / gsum;
        const int tg = tok0 + t;
#pragma unroll
        for (int j = 0; j < TOPK; ++j) {
            g_out[(size_t)tg * TOPK + j] = g[j] * inv;
            i_out[(size_t)tg * TOPK + j] = (float)idx[j];
        }
        if (flag) {
            int p = atomicAdd(flag_cnt, 1);
            if (p < flag_cap) flag_list[p] = tg;
        }
    }
}

// ---------------------------------------------------------------------------
// Kernel 2: f64-exact re-rank of ambiguous tokens.
// ---------------------------------------------------------------------------
__global__ __launch_bounds__(256) void refine_kernel(
    const float* __restrict__ x, const float* __restrict__ W,
    const float* __restrict__ b, float* __restrict__ g_out,
    float* __restrict__ i_out, float* __restrict__ s_out,
    const int* __restrict__ flag_cnt, const int* __restrict__ flag_list,
    int flag_cap)
{
    __shared__ float  xs2[DDIM];
    __shared__ double red[4][NEXP];
    __shared__ double sc[NEXP];

    const int tid = threadIdx.x;
    int count = *flag_cnt;
    if (count > flag_cap) count = flag_cap;

    for (int it = blockIdx.x; it < count; it += gridDim.x) {
        const int tok = flag_list[it];
        __syncthreads();
#pragma unroll
        for (int q = 0; q < 4; ++q) {
            int fi = tid + 256 * q;
            *reinterpret_cast<float4*>(&xs2[fi * 4]) =
                *reinterpret_cast<const float4*>(&x[(size_t)tok * DDIM + fi * 4]);
        }
        __syncthreads();

        const int e    = tid & 63;
        const int part = tid >> 6;
        const int dbase = part * (DDIM / 4);
        double a = 0.0;
        for (int d = 0; d < DDIM / 4; ++d) {
            a = fma((double)xs2[dbase + d],
                    (double)W[(size_t)(dbase + d) * NEXP + e], a);
        }
        red[part][e] = a;
        __syncthreads();

        if (tid < NEXP) {
            double z = ((red[0][tid] + red[1][tid]) +
                        (red[2][tid] + red[3][tid])) + (double)b[tid];
            double s = 1.0 / (1.0 + exp(-z));
            sc[tid] = s;
            s_out[(size_t)tok * NEXP + tid] = (float)s;
        }
        __syncthreads();

        if (tid == 0) {
            double val[TOPK];
            int    idx[TOPK];
#pragma unroll
            for (int j = 0; j < TOPK; ++j) { val[j] = -1e30; idx[j] = 0; }
            for (int e2 = 0; e2 < NEXP; ++e2) {
                double v = sc[e2];
                int   ei = e2;
#pragma unroll
                for (int j = 0; j < TOPK; ++j) {
                    if (v > val[j]) {
                        double tv = val[j]; val[j] = v; v = tv;
                        int    ti = idx[j]; idx[j] = ei; ei = ti;
                    }
                }
            }
            double gsum = 0.0;
#pragma unroll
            for (int j = 0; j < TOPK; ++j) gsum += val[j];
            const double inv = 1.0 / gsum;
#pragma unroll
            for (int j = 0; j < TOPK; ++j) {
                g_out[(size_t)tok * TOPK + j] = (float)(val[j] * inv);
                i_out[(size_t)tok * TOPK + j] = (float)idx[j];
            }
        }
        __syncthreads();
    }
}

// ---------------------------------------------------------------------------
extern "C" void kernel_launch(void* const* d_in, const int* in_sizes, int n_in,
                              void* d_out, int out_size, void* d_ws, size_t ws_size,
                              hipStream_t stream)
{
    (void)in_sizes; (void)n_in; (void)out_size;
    const float* x = (const float*)d_in[0];
    const float* W = (const float*)d_in[1];
    const float* b = (const float*)d_in[2];

    float* g_out = (float*)d_out;                       // [NTOK, 8]
    float* i_out = g_out + (size_t)NTOK * TOPK;         // [NTOK, 8] indices as float
    float* s_out = i_out + (size_t)NTOK * TOPK;         // [NTOK, 64]

    const size_t OFF_LIST = 16;
    const size_t OFF_WHI  = 131072;                             // 128 KB
    const size_t OFF_WLO  = OFF_WHI + (size_t)NEXP * DDIM * 2;  // +512 KB
    const size_t WS_NEED  = OFF_WLO + (size_t)NEXP * DDIM * 2;  // ~1.13 MB
    if (ws_size < WS_NEED) return;

    char* ws = (char*)d_ws;
    int* cnt  = (int*)ws;
    int* list = (int*)(ws + OFF_LIST);
    unsigned short* wt_hi = (unsigned short*)(ws + OFF_WHI);
    unsigned short* wt_lo = (unsigned short*)(ws + OFF_WLO);
    int cap = NTOK;

    hipMemsetAsync(cnt, 0, 16, stream);
    prep_w<<<DDIM / 64, 256, 0, stream>>>(W, wt_hi, wt_lo);
    bulk_kernel<<<NTOK / TPB, 512, 0, stream>>>(x, wt_hi, wt_lo, b,
                                                g_out, i_out, s_out,
                                                cnt, list, cap);
    refine_kernel<<<256, 256, 0, stream>>>(x, W, b, g_out, i_out, s_out,
                                           cnt, list, cap);
}

// Round 4
// 311.211 us; speedup vs baseline: 1.2275x; 1.0086x over previous
//
#include <hip/hip_runtime.h>
#include <cmath>

// Problem constants (B=4, S=4096, D=4096, E=64, K=8)
#define NTOK 16384
#define DDIM 4096
#define NEXP 64
#define TOPK 8
#define TPB  32                  // tokens per block
#define WPB  8                   // waves per block (K-split ways)
#define KSL  (DDIM / WPB)        // 512 K per wave
#define KCPW (KSL / 32)          // 16 k-steps of 32 per wave
#define EPS_GAP 2.5e-4f          // logit-gap ambiguity margin; bf16x2 err ~2-4e-5

typedef __attribute__((ext_vector_type(8))) short short8;   // 8 bf16 (4 VGPRs)
typedef __attribute__((ext_vector_type(4))) float f32x4;

__device__ __forceinline__ unsigned short f2bf(float f) {   // fp32 -> bf16 (RNE)
    unsigned u = __builtin_bit_cast(unsigned, f);
    u += 0x7FFFu + ((u >> 16) & 1u);
    return (unsigned short)(u >> 16);
}
__device__ __forceinline__ float bf2f(unsigned short h) {
    return __builtin_bit_cast(float, ((unsigned)h) << 16);
}

// ---------------------------------------------------------------------------
// Kernel 0: W[4096][64] fp32 -> transposed bf16 hi/lo: Wt[64 experts][4096 k]
// ---------------------------------------------------------------------------
__global__ __launch_bounds__(256) void prep_w(const float* __restrict__ W,
                                              unsigned short* __restrict__ wt_hi,
                                              unsigned short* __restrict__ wt_lo)
{
    __shared__ float tile[64][65];
    const int t = threadIdx.x;
    const int k0 = blockIdx.x * 64;
    {
        const int r = t >> 2, q = t & 3;
#pragma unroll
        for (int p = 0; p < 4; ++p) {
            float4 v = *reinterpret_cast<const float4*>(
                &W[(size_t)(k0 + r) * NEXP + q * 16 + p * 4]);
            tile[r][q * 16 + p * 4 + 0] = v.x;
            tile[r][q * 16 + p * 4 + 1] = v.y;
            tile[r][q * 16 + p * 4 + 2] = v.z;
            tile[r][q * 16 + p * 4 + 3] = v.w;
        }
    }
    __syncthreads();
    {
        const int e = t >> 2, kq = t & 3;
        short8 hv[2], lv[2];
#pragma unroll
        for (int half = 0; half < 2; ++half) {
#pragma unroll
            for (int kk = 0; kk < 8; ++kk) {
                float f = tile[kq * 16 + half * 8 + kk][e];
                unsigned short h = f2bf(f);
                hv[half][kk] = (short)h;
                lv[half][kk] = (short)f2bf(f - bf2f(h));
            }
        }
        size_t base = (size_t)e * DDIM + k0 + kq * 16;
        *reinterpret_cast<short8*>(&wt_hi[base + 0]) = hv[0];
        *reinterpret_cast<short8*>(&wt_hi[base + 8]) = hv[1];
        *reinterpret_cast<short8*>(&wt_lo[base + 0]) = lv[0];
        *reinterpret_cast<short8*>(&wt_lo[base + 8]) = lv[1];
    }
}

// --- hot-loop macros: NAMED registers only, no arrays through pointers ---
#define LDA4(kc, va, vb, vc, vd) do {                        \
    const float* _p0 = xrow0 + (size_t)(kc) * 32;            \
    va = *reinterpret_cast<const float4*>(_p0);              \
    vb = *reinterpret_cast<const float4*>(_p0 + 4);          \
    const float* _p1 = xrow1 + (size_t)(kc) * 32;            \
    vc = *reinterpret_cast<const float4*>(_p1);              \
    vd = *reinterpret_cast<const float4*>(_p1 + 4);          \
} while (0)

#define CVT1(f, hOut, lOut, j) do {                          \
    unsigned short _h = f2bf(f);                             \
    hOut[j] = (short)_h;                                     \
    lOut[j] = (short)f2bf((f) - bf2f(_h));                   \
} while (0)

#define CONV8(vA, vB, hOut, lOut) do {                       \
    CVT1(vA.x, hOut, lOut, 0); CVT1(vA.y, hOut, lOut, 1);    \
    CVT1(vA.z, hOut, lOut, 2); CVT1(vA.w, hOut, lOut, 3);    \
    CVT1(vB.x, hOut, lOut, 4); CVT1(vB.y, hOut, lOut, 5);    \
    CVT1(vB.z, hOut, lOut, 6); CVT1(vB.w, hOut, lOut, 7);    \
} while (0)

#define PROCESS(kc) do {                                                            \
    const size_t _kb = (size_t)(kc) * 32;                                           \
    _Pragma("unroll")                                                               \
    for (int n = 0; n < 4; ++n) {                                                   \
        short8 _bh = *reinterpret_cast<const short8*>(&whb[(size_t)n * 16 * DDIM + _kb]); \
        short8 _bl = *reinterpret_cast<const short8*>(&wlb[(size_t)n * 16 * DDIM + _kb]); \
        acc0[n] = __builtin_amdgcn_mfma_f32_16x16x32_bf16(ah0, _bh, acc0[n], 0, 0, 0);    \
        acc0[n] = __builtin_amdgcn_mfma_f32_16x16x32_bf16(ah0, _bl, acc0[n], 0, 0, 0);    \
        acc0[n] = __builtin_amdgcn_mfma_f32_16x16x32_bf16(al0, _bh, acc0[n], 0, 0, 0);    \
        acc1[n] = __builtin_amdgcn_mfma_f32_16x16x32_bf16(ah1, _bh, acc1[n], 0, 0, 0);    \
        acc1[n] = __builtin_amdgcn_mfma_f32_16x16x32_bf16(ah1, _bl, acc1[n], 0, 0, 0);    \
        acc1[n] = __builtin_amdgcn_mfma_f32_16x16x32_bf16(al1, _bh, acc1[n], 0, 0, 0);    \
    }                                                                               \
} while (0)

// ---------------------------------------------------------------------------
// Kernel 1: bulk MFMA GEMM, K-split 8 ways across waves + LDS reduce.
// 512 blocks x 512 thr (8 waves). Block = 32 tokens x 64 experts.
// ---------------------------------------------------------------------------
__global__ __launch_bounds__(512, 4) void bulk_kernel(
    const float* __restrict__ x,
    const unsigned short* __restrict__ wt_hi,
    const unsigned short* __restrict__ wt_lo,
    const float* __restrict__ b,
    float* __restrict__ g_out, float* __restrict__ i_out,
    float* __restrict__ s_out,
    int* __restrict__ flag_cnt, int* __restrict__ flag_list, int flag_cap)
{
    __shared__ float red[WPB][TPB][NEXP];   // 64 KB partial accumulators
    __shared__ float ls[TPB][NEXP + 1];     // padded logits for the scan

    const int tid  = threadIdx.x;
    const int l    = tid & 63;
    const int wid  = tid >> 6;
    const int tok0 = blockIdx.x * TPB;

    const int lrow = l & 15;
    const int kgrp = l >> 4;
    const int koff = kgrp * 8;
    const int kbase = wid * KSL;

    const float* xrow0 = x + (size_t)(tok0 + lrow) * DDIM + kbase + koff;
    const float* xrow1 = xrow0 + (size_t)16 * DDIM;
    const unsigned short* whb = wt_hi + (size_t)lrow * DDIM + kbase + koff;
    const unsigned short* wlb = wt_lo + (size_t)lrow * DDIM + kbase + koff;

    f32x4 acc0[4], acc1[4];
#pragma unroll
    for (int n = 0; n < 4; ++n) {
        acc0[n] = (f32x4){0.f, 0.f, 0.f, 0.f};
        acc1[n] = (f32x4){0.f, 0.f, 0.f, 0.f};
    }

    float4 xa0, xa1, xa2, xa3, xb0, xb1, xb2, xb3;
    short8 ah0, al0, ah1, al1;

    LDA4(0, xa0, xa1, xa2, xa3);
    LDA4(1, xb0, xb1, xb2, xb3);
    for (int kc2 = 0; kc2 < KCPW / 2; ++kc2) {
        const int kc = 2 * kc2;
        CONV8(xa0, xa1, ah0, al0);
        CONV8(xa2, xa3, ah1, al1);
        { const int nk = (kc + 2 < KCPW) ? kc + 2 : KCPW - 2;
          LDA4(nk, xa0, xa1, xa2, xa3); }
        PROCESS(kc);
        CONV8(xb0, xb1, ah0, al0);
        CONV8(xb2, xb3, ah1, al1);
        { const int nk = (kc + 3 < KCPW) ? kc + 3 : KCPW - 1;
          LDA4(nk, xb0, xb1, xb2, xb3); }
        PROCESS(kc + 1);
    }

    // partial accumulators -> LDS
#pragma unroll
    for (int n = 0; n < 4; ++n)
#pragma unroll
        for (int r = 0; r < 4; ++r) {
            red[wid][kgrp * 4 + r][n * 16 + lrow]      = acc0[n][r];
            red[wid][16 + kgrp * 4 + r][n * 16 + lrow] = acc1[n][r];
        }
    __syncthreads();

    // deterministic fixed-order reduce + bias + sigmoid + s_out write
    {
        const int t  = tid >> 4;           // token 0..31
        const int e0 = (tid & 15) * 4;     // expert base 0..60
        float s0 = red[0][t][e0 + 0], s1 = red[0][t][e0 + 1];
        float s2 = red[0][t][e0 + 2], s3 = red[0][t][e0 + 3];
#pragma unroll
        for (int w = 1; w < WPB; ++w) {
            s0 += red[w][t][e0 + 0];
            s1 += red[w][t][e0 + 1];
            s2 += red[w][t][e0 + 2];
            s3 += red[w][t][e0 + 3];
        }
        float4 bv = *reinterpret_cast<const float4*>(&b[e0]);
        s0 += bv.x; s1 += bv.y; s2 += bv.z; s3 += bv.w;
        ls[t][e0 + 0] = s0; ls[t][e0 + 1] = s1;
        ls[t][e0 + 2] = s2; ls[t][e0 + 3] = s3;
        float4 sv;
        sv.x = 1.0f / (1.0f + __expf(-s0));
        sv.y = 1.0f / (1.0f + __expf(-s1));
        sv.z = 1.0f / (1.0f + __expf(-s2));
        sv.w = 1.0f / (1.0f + __expf(-s3));
        *reinterpret_cast<float4*>(&s_out[(size_t)(tok0 + t) * NEXP + e0]) = sv;
    }
    __syncthreads();

    // top-10 scan, one lane per token (32 lanes of wave 0)
    if (tid < TPB) {
        const int t = tid;
        float val[10];
        int   idx[10];
#pragma unroll
        for (int j = 0; j < 10; ++j) { val[j] = -1e30f; idx[j] = 0; }

        for (int e = 0; e < NEXP; ++e) {
            float v = ls[t][e];
            int  ei = e;
#pragma unroll
            for (int j = 0; j < 10; ++j) {
                if (v > val[j]) {    // strict > keeps lower index first on ties
                    float tv = val[j]; val[j] = v; v = tv;
                    int   ti = idx[j]; idx[j] = ei; ei = ti;
                }
            }
        }

        bool flag = false;
#pragma unroll
        for (int j = 0; j < 9; ++j) flag |= (val[j] - val[j + 1]) < EPS_GAP;

        float g[TOPK], gsum = 0.0f;
#pragma unroll
        for (int j = 0; j < TOPK; ++j) {
            g[j] = 1.0f / (1.0f + __expf(-val[j]));
            gsum += g[j];
        }
        const float inv = 1.0f / gsum;
        const int tg = tok0 + t;
#pragma unroll
        for (int j = 0; j < TOPK; ++j) {
            g_out[(size_t)tg * TOPK + j] = g[j] * inv;
            i_out[(size_t)tg * TOPK + j] = (float)idx[j];
        }
        if (flag) {
            int p = atomicAdd(flag_cnt, 1);
            if (p < flag_cap) flag_list[p] = tg;
        }
    }
}

// ---------------------------------------------------------------------------
// Kernel 2: f64-exact re-rank of ambiguous tokens.
// ---------------------------------------------------------------------------
__global__ __launch_bounds__(256) void refine_kernel(
    const float* __restrict__ x, const float* __restrict__ W,
    const float* __restrict__ b, float* __restrict__ g_out,
    float* __restrict__ i_out, float* __restrict__ s_out,
    const int* __restrict__ flag_cnt, const int* __restrict__ flag_list,
    int flag_cap)
{
    __shared__ float  xs2[DDIM];
    __shared__ double red[4][NEXP];
    __shared__ double sc[NEXP];

    const int tid = threadIdx.x;
    int count = *flag_cnt;
    if (count > flag_cap) count = flag_cap;

    for (int it = blockIdx.x; it < count; it += gridDim.x) {
        const int tok = flag_list[it];
        __syncthreads();
#pragma unroll
        for (int q = 0; q < 4; ++q) {
            int fi = tid + 256 * q;
            *reinterpret_cast<float4*>(&xs2[fi * 4]) =
                *reinterpret_cast<const float4*>(&x[(size_t)tok * DDIM + fi * 4]);
        }
        __syncthreads();

        const int e    = tid & 63;
        const int part = tid >> 6;
        const int dbase = part * (DDIM / 4);
        double a = 0.0;
        for (int d = 0; d < DDIM / 4; ++d) {
            a = fma((double)xs2[dbase + d],
                    (double)W[(size_t)(dbase + d) * NEXP + e], a);
        }
        red[part][e] = a;
        __syncthreads();

        if (tid < NEXP) {
            double z = ((red[0][tid] + red[1][tid]) +
                        (red[2][tid] + red[3][tid])) + (double)b[tid];
            double s = 1.0 / (1.0 + exp(-z));
            sc[tid] = s;
            s_out[(size_t)tok * NEXP + tid] = (float)s;
        }
        __syncthreads();

        if (tid == 0) {
            double val[TOPK];
            int    idx[TOPK];
#pragma unroll
            for (int j = 0; j < TOPK; ++j) { val[j] = -1e30; idx[j] = 0; }
            for (int e2 = 0; e2 < NEXP; ++e2) {
                double v = sc[e2];
                int   ei = e2;
#pragma unroll
                for (int j = 0; j < TOPK; ++j) {
                    if (v > val[j]) {
                        double tv = val[j]; val[j] = v; v = tv;
                        int    ti = idx[j]; idx[j] = ei; ei = ti;
                    }
                }
            }
            double gsum = 0.0;
#pragma unroll
            for (int j = 0; j < TOPK; ++j) gsum += val[j];
            const double inv = 1.0 / gsum;
#pragma unroll
            for (int j = 0; j < TOPK; ++j) {
                g_out[(size_t)tok * TOPK + j] = (float)(val[j] * inv);
                i_out[(size_t)tok * TOPK + j] = (float)idx[j];
            }
        }
        __syncthreads();
    }
}

// ---------------------------------------------------------------------------
extern "C" void kernel_launch(void* const* d_in, const int* in_sizes, int n_in,
                              void* d_out, int out_size, void* d_ws, size_t ws_size,
                              hipStream_t stream)
{
    (void)in_sizes; (void)n_in; (void)out_size;
    const float* x = (const float*)d_in[0];
    const float* W = (const float*)d_in[1];
    const float* b = (const float*)d_in[2];

    float* g_out = (float*)d_out;                       // [NTOK, 8]
    float* i_out = g_out + (size_t)NTOK * TOPK;         // [NTOK, 8] indices as float
    float* s_out = i_out + (size_t)NTOK * TOPK;         // [NTOK, 64]

    const size_t OFF_LIST = 16;
    const size_t OFF_WHI  = 131072;                             // 128 KB
    const size_t OFF_WLO  = OFF_WHI + (size_t)NEXP * DDIM * 2;  // +512 KB
    const size_t WS_NEED  = OFF_WLO + (size_t)NEXP * DDIM * 2;  // ~1.13 MB
    if (ws_size < WS_NEED) return;

    char* ws = (char*)d_ws;
    int* cnt  = (int*)ws;
    int* list = (int*)(ws + OFF_LIST);
    unsigned short* wt_hi = (unsigned short*)(ws + OFF_WHI);
    unsigned short* wt_lo = (unsigned short*)(ws + OFF_WLO);
    int cap = NTOK;

    hipMemsetAsync(cnt, 0, 16, stream);
    prep_w<<<DDIM / 64, 256, 0, stream>>>(W, wt_hi, wt_lo);
    bulk_kernel<<<NTOK / TPB, 512, 0, stream>>>(x, wt_hi, wt_lo, b,
                                                g_out, i_out, s_out,
                                                cnt, list, cap);
    refine_kernel<<<256, 256, 0, stream>>>(x, W, b, g_out, i_out, s_out,
                                           cnt, list, cap);
}

// Round 5
// 302.776 us; speedup vs baseline: 1.2617x; 1.0279x over previous
//
#include <hip/hip_runtime.h>
#include <cmath>

// Problem constants (B=4, S=4096, D=4096, E=64, K=8)
#define NTOK 16384
#define DDIM 4096
#define NEXP 64
#define TOPK 8
#define TPB  32                  // tokens per block
#define WPB  8                   // waves per block (K-split ways)
#define KSL  (DDIM / WPB)        // 512 K per wave
#define KCPW (KSL / 32)          // 16 k-steps of 32 per wave
#define EPS_GAP 2.5e-4f          // logit-gap ambiguity margin; bf16x2 err ~2-4e-5

typedef __attribute__((ext_vector_type(8))) short short8;   // 8 bf16 (4 VGPRs)
typedef __attribute__((ext_vector_type(4))) float f32x4;

__device__ __forceinline__ unsigned short f2bf(float f) {   // fp32 -> bf16 (RNE)
    unsigned u = __builtin_bit_cast(unsigned, f);
    u += 0x7FFFu + ((u >> 16) & 1u);
    return (unsigned short)(u >> 16);
}
__device__ __forceinline__ float bf2f(unsigned short h) {
    return __builtin_bit_cast(float, ((unsigned)h) << 16);
}

// ---------------------------------------------------------------------------
// Kernel 0: W[4096][64] fp32 -> transposed bf16 hi/lo: Wt[64 experts][4096 k]
// ---------------------------------------------------------------------------
__global__ __launch_bounds__(256) void prep_w(const float* __restrict__ W,
                                              unsigned short* __restrict__ wt_hi,
                                              unsigned short* __restrict__ wt_lo)
{
    __shared__ float tile[64][65];
    const int t = threadIdx.x;
    const int k0 = blockIdx.x * 64;
    {
        const int r = t >> 2, q = t & 3;
#pragma unroll
        for (int p = 0; p < 4; ++p) {
            float4 v = *reinterpret_cast<const float4*>(
                &W[(size_t)(k0 + r) * NEXP + q * 16 + p * 4]);
            tile[r][q * 16 + p * 4 + 0] = v.x;
            tile[r][q * 16 + p * 4 + 1] = v.y;
            tile[r][q * 16 + p * 4 + 2] = v.z;
            tile[r][q * 16 + p * 4 + 3] = v.w;
        }
    }
    __syncthreads();
    {
        const int e = t >> 2, kq = t & 3;
        short8 hv[2], lv[2];
#pragma unroll
        for (int half = 0; half < 2; ++half) {
#pragma unroll
            for (int kk = 0; kk < 8; ++kk) {
                float f = tile[kq * 16 + half * 8 + kk][e];
                unsigned short h = f2bf(f);
                hv[half][kk] = (short)h;
                lv[half][kk] = (short)f2bf(f - bf2f(h));
            }
        }
        size_t base = (size_t)e * DDIM + k0 + kq * 16;
        *reinterpret_cast<short8*>(&wt_hi[base + 0]) = hv[0];
        *reinterpret_cast<short8*>(&wt_hi[base + 8]) = hv[1];
        *reinterpret_cast<short8*>(&wt_lo[base + 0]) = lv[0];
        *reinterpret_cast<short8*>(&wt_lo[base + 8]) = lv[1];
    }
}

// --- hot-loop macros: NAMED registers only ---
#define LDA4(kc, va, vb, vc, vd) do {                        \
    const float* _p0 = xrow0 + (size_t)(kc) * 32;            \
    va = *reinterpret_cast<const float4*>(_p0);              \
    vb = *reinterpret_cast<const float4*>(_p0 + 4);          \
    const float* _p1 = xrow1 + (size_t)(kc) * 32;            \
    vc = *reinterpret_cast<const float4*>(_p1);              \
    vd = *reinterpret_cast<const float4*>(_p1 + 4);          \
} while (0)

#define CVT1(f, hOut, lOut, j) do {                          \
    unsigned short _h = f2bf(f);                             \
    hOut[j] = (short)_h;                                     \
    lOut[j] = (short)f2bf((f) - bf2f(_h));                   \
} while (0)

#define CONV8(vA, vB, hOut, lOut) do {                       \
    CVT1(vA.x, hOut, lOut, 0); CVT1(vA.y, hOut, lOut, 1);    \
    CVT1(vA.z, hOut, lOut, 2); CVT1(vA.w, hOut, lOut, 3);    \
    CVT1(vB.x, hOut, lOut, 4); CVT1(vB.y, hOut, lOut, 5);    \
    CVT1(vB.z, hOut, lOut, 6); CVT1(vB.w, hOut, lOut, 7);    \
} while (0)

#define PROCESS(kc) do {                                                            \
    const size_t _kb = (size_t)(kc) * 32;                                           \
    _Pragma("unroll")                                                               \
    for (int n = 0; n < 4; ++n) {                                                   \
        short8 _bh = *reinterpret_cast<const short8*>(&whb[(size_t)n * 16 * DDIM + _kb]); \
        short8 _bl = *reinterpret_cast<const short8*>(&wlb[(size_t)n * 16 * DDIM + _kb]); \
        acc0[n] = __builtin_amdgcn_mfma_f32_16x16x32_bf16(ah0, _bh, acc0[n], 0, 0, 0);    \
        acc0[n] = __builtin_amdgcn_mfma_f32_16x16x32_bf16(ah0, _bl, acc0[n], 0, 0, 0);    \
        acc0[n] = __builtin_amdgcn_mfma_f32_16x16x32_bf16(al0, _bh, acc0[n], 0, 0, 0);    \
        acc1[n] = __builtin_amdgcn_mfma_f32_16x16x32_bf16(ah1, _bh, acc1[n], 0, 0, 0);    \
        acc1[n] = __builtin_amdgcn_mfma_f32_16x16x32_bf16(ah1, _bl, acc1[n], 0, 0, 0);    \
        acc1[n] = __builtin_amdgcn_mfma_f32_16x16x32_bf16(al1, _bh, acc1[n], 0, 0, 0);    \
    }                                                                               \
} while (0)

// ---------------------------------------------------------------------------
// Kernel 1: bulk MFMA GEMM, K-split 8 ways across waves + LDS reduce.
// 512 blocks x 512 thr (8 waves). Block = 32 tokens x 64 experts.
// launch_bounds min-waves/EU = 2: LDS already caps at 2 blocks/CU (4 waves/
// SIMD); asking for 4 waves/EU capped unified regs at 128 -> spill (R3/R4
// WRITE_SIZE 94-127 MB). 2 gives 256-reg budget, no spill, same occupancy.
// ---------------------------------------------------------------------------
__global__ __launch_bounds__(512, 2) void bulk_kernel(
    const float* __restrict__ x,
    const unsigned short* __restrict__ wt_hi,
    const unsigned short* __restrict__ wt_lo,
    const float* __restrict__ b,
    float* __restrict__ g_out, float* __restrict__ i_out,
    float* __restrict__ s_out,
    int* __restrict__ flag_cnt, int* __restrict__ flag_list, int flag_cap)
{
    __shared__ float red[WPB][TPB][NEXP];   // 64 KB partial accumulators
    __shared__ float ls[TPB][NEXP + 1];     // padded logits for the scan

    const int tid  = threadIdx.x;
    const int l    = tid & 63;
    const int wid  = tid >> 6;
    const int tok0 = blockIdx.x * TPB;

    const int lrow = l & 15;
    const int kgrp = l >> 4;
    const int koff = kgrp * 8;
    const int kbase = wid * KSL;

    const float* xrow0 = x + (size_t)(tok0 + lrow) * DDIM + kbase + koff;
    const float* xrow1 = xrow0 + (size_t)16 * DDIM;
    const unsigned short* whb = wt_hi + (size_t)lrow * DDIM + kbase + koff;
    const unsigned short* wlb = wt_lo + (size_t)lrow * DDIM + kbase + koff;

    f32x4 acc0[4], acc1[4];
#pragma unroll
    for (int n = 0; n < 4; ++n) {
        acc0[n] = (f32x4){0.f, 0.f, 0.f, 0.f};
        acc1[n] = (f32x4){0.f, 0.f, 0.f, 0.f};
    }

    float4 xa0, xa1, xa2, xa3, xb0, xb1, xb2, xb3;
    short8 ah0, al0, ah1, al1;

    LDA4(0, xa0, xa1, xa2, xa3);
    LDA4(1, xb0, xb1, xb2, xb3);
    for (int kc2 = 0; kc2 < KCPW / 2; ++kc2) {
        const int kc = 2 * kc2;
        CONV8(xa0, xa1, ah0, al0);
        CONV8(xa2, xa3, ah1, al1);
        { const int nk = (kc + 2 < KCPW) ? kc + 2 : KCPW - 2;
          LDA4(nk, xa0, xa1, xa2, xa3); }
        PROCESS(kc);
        CONV8(xb0, xb1, ah0, al0);
        CONV8(xb2, xb3, ah1, al1);
        { const int nk = (kc + 3 < KCPW) ? kc + 3 : KCPW - 1;
          LDA4(nk, xb0, xb1, xb2, xb3); }
        PROCESS(kc + 1);
    }

    // partial accumulators -> LDS
#pragma unroll
    for (int n = 0; n < 4; ++n)
#pragma unroll
        for (int r = 0; r < 4; ++r) {
            red[wid][kgrp * 4 + r][n * 16 + lrow]      = acc0[n][r];
            red[wid][16 + kgrp * 4 + r][n * 16 + lrow] = acc1[n][r];
        }
    __syncthreads();

    // deterministic fixed-order reduce + bias + sigmoid + s_out write
    {
        const int t  = tid >> 4;           // token 0..31
        const int e0 = (tid & 15) * 4;     // expert base 0..60
        float s0 = red[0][t][e0 + 0], s1 = red[0][t][e0 + 1];
        float s2 = red[0][t][e0 + 2], s3 = red[0][t][e0 + 3];
#pragma unroll
        for (int w = 1; w < WPB; ++w) {
            s0 += red[w][t][e0 + 0];
            s1 += red[w][t][e0 + 1];
            s2 += red[w][t][e0 + 2];
            s3 += red[w][t][e0 + 3];
        }
        float4 bv = *reinterpret_cast<const float4*>(&b[e0]);
        s0 += bv.x; s1 += bv.y; s2 += bv.z; s3 += bv.w;
        ls[t][e0 + 0] = s0; ls[t][e0 + 1] = s1;
        ls[t][e0 + 2] = s2; ls[t][e0 + 3] = s3;
        float4 sv;
        sv.x = 1.0f / (1.0f + __expf(-s0));
        sv.y = 1.0f / (1.0f + __expf(-s1));
        sv.z = 1.0f / (1.0f + __expf(-s2));
        sv.w = 1.0f / (1.0f + __expf(-s3));
        *reinterpret_cast<float4*>(&s_out[(size_t)(tok0 + t) * NEXP + e0]) = sv;
    }
    __syncthreads();

    // top-10 scan, one lane per token (32 lanes of wave 0)
    if (tid < TPB) {
        const int t = tid;
        float val[10];
        int   idx[10];
#pragma unroll
        for (int j = 0; j < 10; ++j) { val[j] = -1e30f; idx[j] = 0; }

        for (int e = 0; e < NEXP; ++e) {
            float v = ls[t][e];
            int  ei = e;
#pragma unroll
            for (int j = 0; j < 10; ++j) {
                if (v > val[j]) {    // strict > keeps lower index first on ties
                    float tv = val[j]; val[j] = v; v = tv;
                    int   ti = idx[j]; idx[j] = ei; ei = ti;
                }
            }
        }

        bool flag = false;
#pragma unroll
        for (int j = 0; j < 9; ++j) flag |= (val[j] - val[j + 1]) < EPS_GAP;

        float g[TOPK], gsum = 0.0f;
#pragma unroll
        for (int j = 0; j < TOPK; ++j) {
            g[j] = 1.0f / (1.0f + __expf(-val[j]));
            gsum += g[j];
        }
        const float inv = 1.0f / gsum;
        const int tg = tok0 + t;
#pragma unroll
        for (int j = 0; j < TOPK; ++j) {
            g_out[(size_t)tg * TOPK + j] = g[j] * inv;
            i_out[(size_t)tg * TOPK + j] = (float)idx[j];
        }
        if (flag) {
            int p = atomicAdd(flag_cnt, 1);
            if (p < flag_cap) flag_list[p] = tg;
        }
    }
}

// ---------------------------------------------------------------------------
// Kernel 2: f64-exact re-rank of ambiguous tokens.
// ---------------------------------------------------------------------------
__global__ __launch_bounds__(256) void refine_kernel(
    const float* __restrict__ x, const float* __restrict__ W,
    const float* __restrict__ b, float* __restrict__ g_out,
    float* __restrict__ i_out, float* __restrict__ s_out,
    const int* __restrict__ flag_cnt, const int* __restrict__ flag_list,
    int flag_cap)
{
    __shared__ float  xs2[DDIM];
    __shared__ double red[4][NEXP];
    __shared__ double sc[NEXP];

    const int tid = threadIdx.x;
    int count = *flag_cnt;
    if (count > flag_cap) count = flag_cap;

    for (int it = blockIdx.x; it < count; it += gridDim.x) {
        const int tok = flag_list[it];
        __syncthreads();
#pragma unroll
        for (int q = 0; q < 4; ++q) {
            int fi = tid + 256 * q;
            *reinterpret_cast<float4*>(&xs2[fi * 4]) =
                *reinterpret_cast<const float4*>(&x[(size_t)tok * DDIM + fi * 4]);
        }
        __syncthreads();

        const int e    = tid & 63;
        const int part = tid >> 6;
        const int dbase = part * (DDIM / 4);
        double a = 0.0;
        for (int d = 0; d < DDIM / 4; ++d) {
            a = fma((double)xs2[dbase + d],
                    (double)W[(size_t)(dbase + d) * NEXP + e], a);
        }
        red[part][e] = a;
        __syncthreads();

        if (tid < NEXP) {
            double z = ((red[0][tid] + red[1][tid]) +
                        (red[2][tid] + red[3][tid])) + (double)b[tid];
            double s = 1.0 / (1.0 + exp(-z));
            sc[tid] = s;
            s_out[(size_t)tok * NEXP + tid] = (float)s;
        }
        __syncthreads();

        if (tid == 0) {
            double val[TOPK];
            int    idx[TOPK];
#pragma unroll
            for (int j = 0; j < TOPK; ++j) { val[j] = -1e30; idx[j] = 0; }
            for (int e2 = 0; e2 < NEXP; ++e2) {
                double v = sc[e2];
                int   ei = e2;
#pragma unroll
                for (int j = 0; j < TOPK; ++j) {
                    if (v > val[j]) {
                        double tv = val[j]; val[j] = v; v = tv;
                        int    ti = idx[j]; idx[j] = ei; ei = ti;
                    }
                }
            }
            double gsum = 0.0;
#pragma unroll
            for (int j = 0; j < TOPK; ++j) gsum += val[j];
            const double inv = 1.0 / gsum;
#pragma unroll
            for (int j = 0; j < TOPK; ++j) {
                g_out[(size_t)tok * TOPK + j] = (float)(val[j] * inv);
                i_out[(size_t)tok * TOPK + j] = (float)idx[j];
            }
        }
        __syncthreads();
    }
}

// ---------------------------------------------------------------------------
extern "C" void kernel_launch(void* const* d_in, const int* in_sizes, int n_in,
                              void* d_out, int out_size, void* d_ws, size_t ws_size,
                              hipStream_t stream)
{
    (void)in_sizes; (void)n_in; (void)out_size;
    const float* x = (const float*)d_in[0];
    const float* W = (const float*)d_in[1];
    const float* b = (const float*)d_in[2];

    float* g_out = (float*)d_out;                       // [NTOK, 8]
    float* i_out = g_out + (size_t)NTOK * TOPK;         // [NTOK, 8] indices as float
    float* s_out = i_out + (size_t)NTOK * TOPK;         // [NTOK, 64]

    const size_t OFF_LIST = 16;
    const size_t OFF_WHI  = 131072;                             // 128 KB
    const size_t OFF_WLO  = OFF_WHI + (size_t)NEXP * DDIM * 2;  // +512 KB
    const size_t WS_NEED  = OFF_WLO + (size_t)NEXP * DDIM * 2;  // ~1.13 MB
    if (ws_size < WS_NEED) return;

    char* ws = (char*)d_ws;
    int* cnt  = (int*)ws;
    int* list = (int*)(ws + OFF_LIST);
    unsigned short* wt_hi = (unsigned short*)(ws + OFF_WHI);
    unsigned short* wt_lo = (unsigned short*)(ws + OFF_WLO);
    int cap = NTOK;

    hipMemsetAsync(cnt, 0, 16, stream);
    prep_w<<<DDIM / 64, 256, 0, stream>>>(W, wt_hi, wt_lo);
    bulk_kernel<<<NTOK / TPB, 512, 0, stream>>>(x, wt_hi, wt_lo, b,
                                                g_out, i_out, s_out,
                                                cnt, list, cap);
    refine_kernel<<<256, 256, 0, stream>>>(x, W, b, g_out, i_out, s_out,
                                           cnt, list, cap);
}

// Round 6
// 215.075 us; speedup vs baseline: 1.7761x; 1.4078x over previous
//
#include <hip/hip_runtime.h>
#include <cmath>

// Problem constants (B=4, S=4096, D=4096, E=64, K=8)
#define NTOK 16384
#define DDIM 4096
#define NEXP 64
#define TOPK 8
#define BT   64                 // tokens per block
#define BK   128                // K per staged step
#define NSTEP (DDIM / BK)       // 32
#define EPS_GAP 2.5e-4f         // ambiguity margin; bf16x2 GEMM err ~1e-5

typedef __attribute__((ext_vector_type(8))) short short8;   // 8 bf16
typedef __attribute__((ext_vector_type(4))) float f32x4;

__device__ __forceinline__ unsigned short f2bf(float f) {   // fp32 -> bf16 RNE
    unsigned u = __builtin_bit_cast(unsigned, f);
    u += 0x7FFFu + ((u >> 16) & 1u);
    return (unsigned short)(u >> 16);
}
__device__ __forceinline__ float bf2f(unsigned short h) {
    return __builtin_bit_cast(float, ((unsigned)h) << 16);
}

__device__ __forceinline__ void gload16(const void* g, void* l) {
    __builtin_amdgcn_global_load_lds(
        (const __attribute__((address_space(1))) unsigned int*)g,
        (__attribute__((address_space(3))) unsigned int*)l, 16, 0, 0);
}

// ---------------------------------------------------------------------------
// Kernel 0: pack W[4096][64] fp32 into the swizzled LDS image:
// blob[chunk c][h=hi/lo][e][128 k as bf16, 16B-groups XOR ((e&7)<<4)]
// 32 chunks x 32 KB = 1 MB. Bulk B-staging then is linear contiguous.
// ---------------------------------------------------------------------------
__global__ __launch_bounds__(256) void prep_w(const float* __restrict__ W,
                                              unsigned char* __restrict__ blob)
{
    __shared__ float tile[BK][NEXP + 1];
    const int c = blockIdx.x;
    const int t = threadIdx.x;
    {
        const int r = t >> 1, ch = (t & 1) * 32;
#pragma unroll
        for (int p = 0; p < 8; ++p) {
            float4 v = *reinterpret_cast<const float4*>(
                &W[(size_t)(c * BK + r) * NEXP + ch + p * 4]);
            tile[r][ch + p * 4 + 0] = v.x;
            tile[r][ch + p * 4 + 1] = v.y;
            tile[r][ch + p * 4 + 2] = v.z;
            tile[r][ch + p * 4 + 3] = v.w;
        }
    }
    __syncthreads();
    {
        const int e = t >> 2, q = t & 3;          // expert, k-quarter (32 k)
        const int exr = (e & 7) << 4;
#pragma unroll
        for (int g = 0; g < 4; ++g) {
            const int k0 = q * 32 + g * 8;
            short8 hv, lv;
#pragma unroll
            for (int j = 0; j < 8; ++j) {
                float f = tile[k0 + j][e];
                unsigned short h = f2bf(f);
                hv[j] = (short)h;
                lv[j] = (short)f2bf(f - bf2f(h));
            }
            const size_t base = (size_t)c * 32768 + (size_t)e * 256 +
                                (((unsigned)(k0 * 2)) ^ exr);
            *reinterpret_cast<short8*>(blob + base)         = hv;   // hi
            *reinterpret_cast<short8*>(blob + base + 16384) = lv;   // lo
        }
    }
}

// --- fp32x8 -> bf16 hi/lo split (named registers) ---
#define CVT1(f, hOut, lOut, j) do {                          \
    unsigned short _h = f2bf(f);                             \
    hOut[j] = (short)_h;                                     \
    lOut[j] = (short)f2bf((f) - bf2f(_h));                   \
} while (0)
#define CONV8(vA, vB, hOut, lOut) do {                       \
    CVT1(vA.x, hOut, lOut, 0); CVT1(vA.y, hOut, lOut, 1);    \
    CVT1(vA.z, hOut, lOut, 2); CVT1(vA.w, hOut, lOut, 3);    \
    CVT1(vB.x, hOut, lOut, 4); CVT1(vB.y, hOut, lOut, 5);    \
    CVT1(vB.z, hOut, lOut, 6); CVT1(vB.w, hOut, lOut, 7);    \
} while (0)

// ---------------------------------------------------------------------------
// Kernel 1: LDS-staged MFMA GEMM. 256 blocks x 512 thr (8 waves).
// Block = 64 tokens x 64 experts, full K. Wave = 16 tokens x 32 experts.
// 2-phase pipeline: STAGE(next) || compute(cur); one barrier per step.
// A LDS image: [token][128k fp32], 16B groups XOR ((token&7)<<4) (staged via
// pre-swizzled per-lane global srcs). B image pre-baked by prep_w.
// ---------------------------------------------------------------------------
__global__ __launch_bounds__(512, 2) void bulk_kernel(
    const float* __restrict__ x, const unsigned char* __restrict__ blob,
    const float* __restrict__ b,
    float* __restrict__ g_out, float* __restrict__ i_out,
    float* __restrict__ s_out,
    int* __restrict__ flag_cnt, int* __restrict__ flag_list, int flag_cap)
{
    __shared__ __align__(16) unsigned char smem[131072];  // A[2][32K] B[2][32K]
    unsigned char* As = smem;
    unsigned char* Bs = smem + 65536;

    const int tid  = threadIdx.x;
    const int l    = tid & 63;
    const int w    = tid >> 6;
    const int tok0 = blockIdx.x * BT;

    // ---- staging source pointers (per-lane, pre-swizzled for A) ----
#define AMAKE(i)                                                              \
    const int oA##i = w * 4096 + i * 1024 + l * 16;                           \
    const int tokA##i = oA##i >> 9;                                           \
    const float* aSrc##i = x + (size_t)(tok0 + tokA##i) * DDIM +              \
        ((((unsigned)(oA##i & 511)) ^ ((tokA##i & 7) << 4)) >> 2);
    AMAKE(0) AMAKE(1) AMAKE(2) AMAKE(3)
#undef AMAKE
    const unsigned char* bSrc = blob + w * 4096 + l * 16;

#define STAGE(bufsel, c) do {                                                 \
    unsigned char* _a = As + (bufsel) * 32768 + w * 4096;                     \
    unsigned char* _b = Bs + (bufsel) * 32768 + w * 4096;                     \
    gload16(aSrc0 + (size_t)(c) * BK, _a + 0);                                \
    gload16(aSrc1 + (size_t)(c) * BK, _a + 1024);                             \
    gload16(aSrc2 + (size_t)(c) * BK, _a + 2048);                             \
    gload16(aSrc3 + (size_t)(c) * BK, _a + 3072);                             \
    gload16(bSrc + (size_t)(c) * 32768 + 0,    _b + 0);                       \
    gload16(bSrc + (size_t)(c) * 32768 + 1024, _b + 1024);                    \
    gload16(bSrc + (size_t)(c) * 32768 + 2048, _b + 2048);                    \
    gload16(bSrc + (size_t)(c) * 32768 + 3072, _b + 3072);                    \
} while (0)

    // ---- compute-lane constants ----
    const int myTok = (w & 3) * 16 + (l & 15);    // token row in block
    const int kgrp  = l >> 4;                     // k-group 0..3
    const int myE0  = (w >> 2) * 32 + (l & 15);   // expert, n=0 frag
    const int axor  = (myTok & 7) << 4;
    const int exor  = (myE0 & 7) << 4;            // same for e0 and e0+16

    f32x4 acc[2];
    acc[0] = (f32x4){0.f, 0.f, 0.f, 0.f};
    acc[1] = (f32x4){0.f, 0.f, 0.f, 0.f};

#define COMPUTE(bufsel) do {                                                  \
    const unsigned char* _ab = As + (bufsel) * 32768 + myTok * 512;           \
    const unsigned char* _bb = Bs + (bufsel) * 32768;                         \
    _Pragma("unroll")                                                         \
    for (int s = 0; s < 4; ++s) {                                             \
        const int _ak = s * 128 + kgrp * 32;                                  \
        float4 A0 = *reinterpret_cast<const float4*>(_ab + ((_ak +  0) ^ axor)); \
        float4 A1 = *reinterpret_cast<const float4*>(_ab + ((_ak + 16) ^ axor)); \
        short8 ah, al;                                                        \
        CONV8(A0, A1, ah, al);                                                \
        const int _bk = (s * 64 + kgrp * 16) ^ exor;                          \
        _Pragma("unroll")                                                     \
        for (int n = 0; n < 2; ++n) {                                         \
            const int _e = myE0 + n * 16;                                     \
            short8 bh = *reinterpret_cast<const short8*>(_bb + _e * 256 + _bk);\
            short8 bl = *reinterpret_cast<const short8*>(_bb + 16384 + _e * 256 + _bk);\
            acc[n] = __builtin_amdgcn_mfma_f32_16x16x32_bf16(ah, bh, acc[n], 0, 0, 0); \
            acc[n] = __builtin_amdgcn_mfma_f32_16x16x32_bf16(ah, bl, acc[n], 0, 0, 0); \
            acc[n] = __builtin_amdgcn_mfma_f32_16x16x32_bf16(al, bh, acc[n], 0, 0, 0); \
        }                                                                     \
    }                                                                         \
} while (0)

    STAGE(0, 0);
    __syncthreads();
    for (int c = 0; c < NSTEP; ++c) {
        const int cur = c & 1;
        if (c + 1 < NSTEP) STAGE(cur ^ 1, c + 1);
        COMPUTE(cur);
        __syncthreads();   // drains vmcnt (stage c+1 landed) + frees buf cur
    }

    // ---- epilogue: bias + sigmoid + logits (ls aliases A buffers) ----
    float* ls = (float*)smem;                     // [64][65]
#pragma unroll
    for (int n = 0; n < 2; ++n) {
        const int e = myE0 + n * 16;
        const float be = b[e];
#pragma unroll
        for (int r = 0; r < 4; ++r) {
            const int token = (w & 3) * 16 + kgrp * 4 + r;
            const float lg = acc[n][r] + be;
            ls[token * 65 + e] = lg;
            s_out[(size_t)(tok0 + token) * NEXP + e] = 1.0f / (1.0f + __expf(-lg));
        }
    }
    __syncthreads();

    // ---- top-10 scan, one lane per token ----
    if (tid < BT) {
        const int t = tid;
        float val[10];
        int   idx[10];
#pragma unroll
        for (int j = 0; j < 10; ++j) { val[j] = -1e30f; idx[j] = 0; }

        for (int e = 0; e < NEXP; ++e) {
            float v = ls[t * 65 + e];
            int  ei = e;
#pragma unroll
            for (int j = 0; j < 10; ++j) {
                if (v > val[j]) {    // strict > keeps lower index first on ties
                    float tv = val[j]; val[j] = v; v = tv;
                    int   ti = idx[j]; idx[j] = ei; ei = ti;
                }
            }
        }

        bool flag = false;
#pragma unroll
        for (int j = 0; j < 9; ++j) flag |= (val[j] - val[j + 1]) < EPS_GAP;

        float g[TOPK], gsum = 0.0f;
#pragma unroll
        for (int j = 0; j < TOPK; ++j) {
            g[j] = 1.0f / (1.0f + __expf(-val[j]));
            gsum += g[j];
        }
        const float inv = 1.0f / gsum;
        const int tg = tok0 + t;
#pragma unroll
        for (int j = 0; j < TOPK; ++j) {
            g_out[(size_t)tg * TOPK + j] = g[j] * inv;
            i_out[(size_t)tg * TOPK + j] = (float)idx[j];
        }
        if (flag) {
            int p = atomicAdd(flag_cnt, 1);
            if (p < flag_cap) flag_list[p] = tg;
        }
    }
#undef STAGE
#undef COMPUTE
}

// ---------------------------------------------------------------------------
// Kernel 2: f64-exact re-rank of ambiguous tokens.
// ---------------------------------------------------------------------------
__global__ __launch_bounds__(256) void refine_kernel(
    const float* __restrict__ x, const float* __restrict__ W,
    const float* __restrict__ b, float* __restrict__ g_out,
    float* __restrict__ i_out, float* __restrict__ s_out,
    const int* __restrict__ flag_cnt, const int* __restrict__ flag_list,
    int flag_cap)
{
    __shared__ float  xs2[DDIM];
    __shared__ double red[4][NEXP];
    __shared__ double sc[NEXP];

    const int tid = threadIdx.x;
    int count = *flag_cnt;
    if (count > flag_cap) count = flag_cap;

    for (int it = blockIdx.x; it < count; it += gridDim.x) {
        const int tok = flag_list[it];
        __syncthreads();
#pragma unroll
        for (int q = 0; q < 4; ++q) {
            int fi = tid + 256 * q;
            *reinterpret_cast<float4*>(&xs2[fi * 4]) =
                *reinterpret_cast<const float4*>(&x[(size_t)tok * DDIM + fi * 4]);
        }
        __syncthreads();

        const int e    = tid & 63;
        const int part = tid >> 6;
        const int dbase = part * (DDIM / 4);
        double a = 0.0;
        for (int d = 0; d < DDIM / 4; ++d) {
            a = fma((double)xs2[dbase + d],
                    (double)W[(size_t)(dbase + d) * NEXP + e], a);
        }
        red[part][e] = a;
        __syncthreads();

        if (tid < NEXP) {
            double z = ((red[0][tid] + red[1][tid]) +
                        (red[2][tid] + red[3][tid])) + (double)b[tid];
            double s = 1.0 / (1.0 + exp(-z));
            sc[tid] = s;
            s_out[(size_t)tok * NEXP + tid] = (float)s;
        }
        __syncthreads();

        if (tid == 0) {
            double val[TOPK];
            int    idx[TOPK];
#pragma unroll
            for (int j = 0; j < TOPK; ++j) { val[j] = -1e30; idx[j] = 0; }
            for (int e2 = 0; e2 < NEXP; ++e2) {
                double v = sc[e2];
                int   ei = e2;
#pragma unroll
                for (int j = 0; j < TOPK; ++j) {
                    if (v > val[j]) {
                        double tv = val[j]; val[j] = v; v = tv;
                        int    ti = idx[j]; idx[j] = ei; ei = ti;
                    }
                }
            }
            double gsum = 0.0;
#pragma unroll
            for (int j = 0; j < TOPK; ++j) gsum += val[j];
            const double inv = 1.0 / gsum;
#pragma unroll
            for (int j = 0; j < TOPK; ++j) {
                g_out[(size_t)tok * TOPK + j] = (float)(val[j] * inv);
                i_out[(size_t)tok * TOPK + j] = (float)idx[j];
            }
        }
        __syncthreads();
    }
}

// ---------------------------------------------------------------------------
extern "C" void kernel_launch(void* const* d_in, const int* in_sizes, int n_in,
                              void* d_out, int out_size, void* d_ws, size_t ws_size,
                              hipStream_t stream)
{
    (void)in_sizes; (void)n_in; (void)out_size;
    const float* x = (const float*)d_in[0];
    const float* W = (const float*)d_in[1];
    const float* b = (const float*)d_in[2];

    float* g_out = (float*)d_out;                       // [NTOK, 8]
    float* i_out = g_out + (size_t)NTOK * TOPK;         // [NTOK, 8] indices as float
    float* s_out = i_out + (size_t)NTOK * TOPK;         // [NTOK, 64]

    const size_t OFF_BLOB = 131072;                     // list: 16..65552
    const size_t WS_NEED  = OFF_BLOB + 32u * 32768u;    // +1 MB blob
    if (ws_size < WS_NEED) return;

    char* ws = (char*)d_ws;
    int* cnt  = (int*)ws;
    int* list = (int*)(ws + 16);
    unsigned char* blob = (unsigned char*)(ws + OFF_BLOB);
    int cap = NTOK;

    hipMemsetAsync(cnt, 0, 16, stream);
    prep_w<<<NSTEP, 256, 0, stream>>>(W, blob);
    bulk_kernel<<<NTOK / BT, 512, 0, stream>>>(x, blob, b,
                                               g_out, i_out, s_out,
                                               cnt, list, cap);
    refine_kernel<<<256, 256, 0, stream>>>(x, W, b, g_out, i_out, s_out,
                                           cnt, list, cap);
}

// Round 7
// 208.025 us; speedup vs baseline: 1.8363x; 1.0339x over previous
//
#include <hip/hip_runtime.h>
#include <cmath>

// Problem constants (B=4, S=4096, D=4096, E=64, K=8)
#define NTOK 16384
#define DDIM 4096
#define NEXP 64
#define TOPK 8
#define TPB  32                 // tokens per block
#define BK   64                 // K per staged step
#define NSTEP (DDIM / BK)       // 64
#define EPS_GAP 2.5e-4f         // ambiguity margin; trunc-split GEMM err sigma ~2e-5

typedef __attribute__((ext_vector_type(8))) short short8;   // 8 bf16
typedef __attribute__((ext_vector_type(4))) float f32x4;

__device__ __forceinline__ void gload16(const void* g, void* l) {
    __builtin_amdgcn_global_load_lds(
        (const __attribute__((address_space(1))) unsigned int*)g,
        (__attribute__((address_space(3))) unsigned int*)l, 16, 0, 0);
}

// trunc split: hi = top 16 bits (residual exact), lo = trunc16(f - hi).
// per-elem err <= 2^-16 rel; 3 terms (drop lo*lo, eps_x, eps_w) -> dot sigma ~2e-5.
#define CVT1(f, hOut, lOut, j) do {                                          \
    unsigned _u = __builtin_bit_cast(unsigned, (float)(f));                  \
    float _hf = __builtin_bit_cast(float, _u & 0xFFFF0000u);                 \
    hOut[j] = (short)(_u >> 16);                                             \
    lOut[j] = (short)(__builtin_bit_cast(unsigned, (float)((f) - _hf)) >> 16);\
} while (0)
#define CONV8(vA, vB, hOut, lOut) do {                       \
    CVT1(vA.x, hOut, lOut, 0); CVT1(vA.y, hOut, lOut, 1);    \
    CVT1(vA.z, hOut, lOut, 2); CVT1(vA.w, hOut, lOut, 3);    \
    CVT1(vB.x, hOut, lOut, 4); CVT1(vB.y, hOut, lOut, 5);    \
    CVT1(vB.z, hOut, lOut, 6); CVT1(vB.w, hOut, lOut, 7);    \
} while (0)

// ---------------------------------------------------------------------------
// Kernel 0: pack W[4096][64] into swizzled B chunks:
// chunk c (64 k): e*256B row = [hi 128B | lo 128B], 16B granules XOR ((e&15)<<4).
// 64 chunks x 16 KB = 1 MB. Bulk B-staging is then linear contiguous.
// Also zeroes the flag counter (replaces the memset graph node).
// ---------------------------------------------------------------------------
__global__ __launch_bounds__(256) void prep_w(const float* __restrict__ W,
                                              unsigned char* __restrict__ blob,
                                              int* __restrict__ flag_cnt)
{
    __shared__ float tile[64][65];
    const int c = blockIdx.x;
    const int t = threadIdx.x;
    if (c == 0 && t == 0) *flag_cnt = 0;
    {
        const int r = t >> 2, q = t & 3;
#pragma unroll
        for (int p = 0; p < 4; ++p) {
            float4 v = *reinterpret_cast<const float4*>(
                &W[(size_t)(c * BK + r) * NEXP + q * 16 + p * 4]);
            tile[r][q * 16 + p * 4 + 0] = v.x;
            tile[r][q * 16 + p * 4 + 1] = v.y;
            tile[r][q * 16 + p * 4 + 2] = v.z;
            tile[r][q * 16 + p * 4 + 3] = v.w;
        }
    }
    __syncthreads();
    {
        const int e = t >> 2, q = t & 3;
        const int swz = (e & 15) << 4;
#pragma unroll
        for (int g = 0; g < 2; ++g) {
            const int k0 = q * 16 + g * 8;
            short8 hv, lv;
#pragma unroll
            for (int j = 0; j < 8; ++j) {
                float f = tile[k0 + j][e];
                CVT1(f, hv, lv, j);
            }
            unsigned char* base = blob + (size_t)c * 16384 + e * 256;
            *reinterpret_cast<short8*>(base + ((k0 * 2) ^ swz))       = hv;
            *reinterpret_cast<short8*>(base + ((128 + k0 * 2) ^ swz)) = lv;
        }
    }
}

// ---------------------------------------------------------------------------
// Kernel 1: LDS-staged MFMA GEMM. 512 blocks x 512 thr (8 waves).
// Block = 32 tokens x 64 experts, full K. Wave = 32 tok x 16 exp;
// waves = 4 expert-groups x 2 K-halves (K-split reduced in LDS at end).
// LDS 48 KB (A 2x8K, B 2x16K) -> 2-3 blocks/CU for barrier-drain overlap.
// ---------------------------------------------------------------------------
__global__ __launch_bounds__(512, 2) void bulk_kernel(
    const float* __restrict__ x, const unsigned char* __restrict__ blob,
    const float* __restrict__ b,
    float* __restrict__ g_out, float* __restrict__ i_out,
    float* __restrict__ s_out,
    int* __restrict__ flag_cnt, int* __restrict__ flag_list, int flag_cap)
{
    __shared__ __align__(16) unsigned char smem[49152];  // A[2][8K] | B[2][16K]

    const int tid  = threadIdx.x;
    const int l    = tid & 63;
    const int w    = tid >> 6;
    const int tok0 = blockIdx.x * TPB;

    // ---- staging sources (A pre-swizzled per-lane; B linear from blob) ----
    const int sTok   = tid >> 4;                 // 0..31
    const int sInner = (tid * 16) & 255;
    const float* aSrc = x + (size_t)(tok0 + sTok) * DDIM +
        ((((unsigned)sInner) ^ ((sTok & 15) << 4)) >> 2);
    const unsigned char* bSrc = blob + tid * 16;

#define STAGE(buf, c) do {                                                    \
    gload16(aSrc + (size_t)(c) * BK, smem + (buf) * 8192 + tid * 16);         \
    gload16(bSrc + (size_t)(c) * 16384,                                       \
            smem + 16384 + (buf) * 16384 + tid * 16);                         \
    gload16(bSrc + (size_t)(c) * 16384 + 8192,                                \
            smem + 16384 + (buf) * 16384 + 8192 + tid * 16);                  \
} while (0)

    // ---- compute-lane constants ----
    const int expgrp = w & 3;                    // 4 groups x 16 experts
    const int khalf  = w >> 2;                   // 2 K-halves of 32
    const int mt     = l & 15;                   // token row within frag
    const int kgrp   = l >> 4;                   // k-subgroup 0..3
    const int kk     = khalf * 32 + kgrp * 8;    // k-elem within step
    const int myE    = expgrp * 16 + mt;
    const int aswz   = mt << 4;
    const int aoff0  = mt * 256 + ((kk * 4) ^ aswz);
    const int eswz   = (myE & 15) << 4;
    const int boffh  = myE * 256 + ((kk * 2) ^ eswz);
    const int boffl  = myE * 256 + (((128 + kk * 2)) ^ eswz);

    f32x4 acc0 = (f32x4){0.f, 0.f, 0.f, 0.f};
    f32x4 acc1 = (f32x4){0.f, 0.f, 0.f, 0.f};

#define COMPUTE(buf) do {                                                     \
    const unsigned char* _a = smem + (buf) * 8192;                            \
    const unsigned char* _b = smem + 16384 + (buf) * 16384;                   \
    float4 A00 = *reinterpret_cast<const float4*>(_a + aoff0);                \
    float4 A01 = *reinterpret_cast<const float4*>(_a + (aoff0 ^ 16));         \
    float4 A10 = *reinterpret_cast<const float4*>(_a + 4096 + aoff0);         \
    float4 A11 = *reinterpret_cast<const float4*>(_a + 4096 + (aoff0 ^ 16));  \
    short8 ah0, al0, ah1, al1;                                                \
    CONV8(A00, A01, ah0, al0);                                                \
    CONV8(A10, A11, ah1, al1);                                                \
    short8 bh = *reinterpret_cast<const short8*>(_b + boffh);                 \
    short8 bl = *reinterpret_cast<const short8*>(_b + boffl);                 \
    acc0 = __builtin_amdgcn_mfma_f32_16x16x32_bf16(ah0, bh, acc0, 0, 0, 0);   \
    acc0 = __builtin_amdgcn_mfma_f32_16x16x32_bf16(ah0, bl, acc0, 0, 0, 0);   \
    acc0 = __builtin_amdgcn_mfma_f32_16x16x32_bf16(al0, bh, acc0, 0, 0, 0);   \
    acc1 = __builtin_amdgcn_mfma_f32_16x16x32_bf16(ah1, bh, acc1, 0, 0, 0);   \
    acc1 = __builtin_amdgcn_mfma_f32_16x16x32_bf16(ah1, bl, acc1, 0, 0, 0);   \
    acc1 = __builtin_amdgcn_mfma_f32_16x16x32_bf16(al1, bh, acc1, 0, 0, 0);   \
} while (0)

    STAGE(0, 0);
    __syncthreads();
    for (int c = 0; c < NSTEP; ++c) {
        if (c + 1 < NSTEP) STAGE((c + 1) & 1, c + 1);
        COMPUTE(c & 1);
        __syncthreads();
    }

    // ---- K-split reduce through LDS (reuse staging buffers) ----
    float* red = (float*)smem;                   // [2][32][68]
    float* ls  = (float*)(smem + 17408);         // [32][65]
    {
        float* rh = red + khalf * (32 * 68);
#pragma unroll
        for (int r = 0; r < 4; ++r) {
            rh[(kgrp * 4 + r) * 68 + myE]        = acc0[r];
            rh[(16 + kgrp * 4 + r) * 68 + myE]   = acc1[r];
        }
    }
    __syncthreads();

    // ---- fixed-order sum + bias + sigmoid + s_out + logits to ls ----
    {
        const int t  = tid >> 4;                 // token 0..31
        const int e0 = (tid & 15) * 4;           // expert base
        float4 v0 = *reinterpret_cast<const float4*>(red + t * 68 + e0);
        float4 v1 = *reinterpret_cast<const float4*>(red + 2176 + t * 68 + e0);
        float4 bv = *reinterpret_cast<const float4*>(&b[e0]);
        float s0 = v0.x + v1.x + bv.x;
        float s1 = v0.y + v1.y + bv.y;
        float s2 = v0.z + v1.z + bv.z;
        float s3 = v0.w + v1.w + bv.w;
        ls[t * 65 + e0 + 0] = s0; ls[t * 65 + e0 + 1] = s1;
        ls[t * 65 + e0 + 2] = s2; ls[t * 65 + e0 + 3] = s3;
        float4 sv;
        sv.x = 1.0f / (1.0f + __expf(-s0));
        sv.y = 1.0f / (1.0f + __expf(-s1));
        sv.z = 1.0f / (1.0f + __expf(-s2));
        sv.w = 1.0f / (1.0f + __expf(-s3));
        *reinterpret_cast<float4*>(&s_out[(size_t)(tok0 + t) * NEXP + e0]) = sv;
    }
    __syncthreads();

    // ---- top-10 scan, one lane per token ----
    if (tid < TPB) {
        const int t = tid;
        float val[10];
        int   idx[10];
#pragma unroll
        for (int j = 0; j < 10; ++j) { val[j] = -1e30f; idx[j] = 0; }

        for (int e = 0; e < NEXP; ++e) {
            float v = ls[t * 65 + e];
            int  ei = e;
#pragma unroll
            for (int j = 0; j < 10; ++j) {
                if (v > val[j]) {    // strict > keeps lower index first on ties
                    float tv = val[j]; val[j] = v; v = tv;
                    int   ti = idx[j]; idx[j] = ei; ei = ti;
                }
            }
        }

        bool flag = false;
#pragma unroll
        for (int j = 0; j < 9; ++j) flag |= (val[j] - val[j + 1]) < EPS_GAP;

        float g[TOPK], gsum = 0.0f;
#pragma unroll
        for (int j = 0; j < TOPK; ++j) {
            g[j] = 1.0f / (1.0f + __expf(-val[j]));
            gsum += g[j];
        }
        const float inv = 1.0f / gsum;
        const int tg = tok0 + t;
#pragma unroll
        for (int j = 0; j < TOPK; ++j) {
            g_out[(size_t)tg * TOPK + j] = g[j] * inv;
            i_out[(size_t)tg * TOPK + j] = (float)idx[j];
        }
        if (flag) {
            int p = atomicAdd(flag_cnt, 1);
            if (p < flag_cap) flag_list[p] = tg;
        }
    }
#undef STAGE
#undef COMPUTE
}

// ---------------------------------------------------------------------------
// Kernel 2: f64-exact re-rank of ambiguous tokens.
// ---------------------------------------------------------------------------
__global__ __launch_bounds__(256) void refine_kernel(
    const float* __restrict__ x, const float* __restrict__ W,
    const float* __restrict__ b, float* __restrict__ g_out,
    float* __restrict__ i_out, float* __restrict__ s_out,
    const int* __restrict__ flag_cnt, const int* __restrict__ flag_list,
    int flag_cap)
{
    __shared__ float  xs2[DDIM];
    __shared__ double red[4][NEXP];
    __shared__ double sc[NEXP];

    const int tid = threadIdx.x;
    int count = *flag_cnt;
    if (count > flag_cap) count = flag_cap;

    for (int it = blockIdx.x; it < count; it += gridDim.x) {
        const int tok = flag_list[it];
        __syncthreads();
#pragma unroll
        for (int q = 0; q < 4; ++q) {
            int fi = tid + 256 * q;
            *reinterpret_cast<float4*>(&xs2[fi * 4]) =
                *reinterpret_cast<const float4*>(&x[(size_t)tok * DDIM + fi * 4]);
        }
        __syncthreads();

        const int e    = tid & 63;
        const int part = tid >> 6;
        const int dbase = part * (DDIM / 4);
        double a = 0.0;
        for (int d = 0; d < DDIM / 4; ++d) {
            a = fma((double)xs2[dbase + d],
                    (double)W[(size_t)(dbase + d) * NEXP + e], a);
        }
        red[part][e] = a;
        __syncthreads();

        if (tid < NEXP) {
            double z = ((red[0][tid] + red[1][tid]) +
                        (red[2][tid] + red[3][tid])) + (double)b[tid];
            double s = 1.0 / (1.0 + exp(-z));
            sc[tid] = s;
            s_out[(size_t)tok * NEXP + tid] = (float)s;
        }
        __syncthreads();

        if (tid == 0) {
            double val[TOPK];
            int    idx[TOPK];
#pragma unroll
            for (int j = 0; j < TOPK; ++j) { val[j] = -1e30; idx[j] = 0; }
            for (int e2 = 0; e2 < NEXP; ++e2) {
                double v = sc[e2];
                int   ei = e2;
#pragma unroll
                for (int j = 0; j < TOPK; ++j) {
                    if (v > val[j]) {
                        double tv = val[j]; val[j] = v; v = tv;
                        int    ti = idx[j]; idx[j] = ei; ei = ti;
                    }
                }
            }
            double gsum = 0.0;
#pragma unroll
            for (int j = 0; j < TOPK; ++j) gsum += val[j];
            const double inv = 1.0 / gsum;
#pragma unroll
            for (int j = 0; j < TOPK; ++j) {
                g_out[(size_t)tok * TOPK + j] = (float)(val[j] * inv);
                i_out[(size_t)tok * TOPK + j] = (float)idx[j];
            }
        }
        __syncthreads();
    }
}

// ---------------------------------------------------------------------------
extern "C" void kernel_launch(void* const* d_in, const int* in_sizes, int n_in,
                              void* d_out, int out_size, void* d_ws, size_t ws_size,
                              hipStream_t stream)
{
    (void)in_sizes; (void)n_in; (void)out_size;
    const float* x = (const float*)d_in[0];
    const float* W = (const float*)d_in[1];
    const float* b = (const float*)d_in[2];

    float* g_out = (float*)d_out;                       // [NTOK, 8]
    float* i_out = g_out + (size_t)NTOK * TOPK;         // [NTOK, 8] indices as float
    float* s_out = i_out + (size_t)NTOK * TOPK;         // [NTOK, 64]

    const size_t OFF_BLOB = 131072;
    const size_t WS_NEED  = OFF_BLOB + (size_t)NSTEP * 16384;   // +1 MB blob
    if (ws_size < WS_NEED) return;

    char* ws = (char*)d_ws;
    int* cnt  = (int*)ws;
    int* list = (int*)(ws + 16);
    unsigned char* blob = (unsigned char*)(ws + OFF_BLOB);
    int cap = NTOK;

    prep_w<<<NSTEP, 256, 0, stream>>>(W, blob, cnt);
    bulk_kernel<<<NTOK / TPB, 512, 0, stream>>>(x, blob, b,
                                                g_out, i_out, s_out,
                                                cnt, list, cap);
    refine_kernel<<<256, 256, 0, stream>>>(x, W, b, g_out, i_out, s_out,
                                           cnt, list, cap);
}